// Round 1
// baseline (135.697 us; speedup 1.0000x reference)
//
#include <hip/hip_runtime.h>
#include <hip/hip_bf16.h>

// TinyAttention fused pipeline, bf16 MFMA path.
// ws layout (bytes):
//   qkv bf16 [16384][192]      @ 0          (6,291,456)
//   Vt  bf16 [8][64][2048]     @ 6,291,456  (2,097,152)
//   att bf16 [16384][64]       @ 8,388,608  (2,097,152)
//   Wt  bf16 [192][1536]       @ 10,485,760 (589,824)
//   WtO bf16 [768][64]         @ 11,075,584 (98,304)
// total ~10.7 MiB

typedef __attribute__((ext_vector_type(8))) short short8;
typedef __attribute__((ext_vector_type(4))) float float4v;

#define MFMA16(a, b, c) __builtin_amdgcn_mfma_f32_16x16x32_bf16((a), (b), (c), 0, 0, 0)

static __device__ __forceinline__ unsigned short f2bf(float x) {
  union { float f; unsigned u; } v; v.f = x;
  return (unsigned short)((v.u + 0x7FFFu + ((v.u >> 16) & 1u)) >> 16);
}
static __device__ __forceinline__ short8 ldg8(const short* p) {
  return *(const short8*)p;
}

// ---------------------------------------------------------------------------
// k_prep: W_qkv [1536][192] f32 -> Wt [192][1536] bf16 (blocks 0..71)
//         W_out [64][768]  f32 -> WtO [768][64]  bf16 (blocks 72..83)
// ---------------------------------------------------------------------------
__global__ __launch_bounds__(256) void k_prep(
    const float* __restrict__ Wq, const float* __restrict__ Wo,
    short* __restrict__ Wt, short* __restrict__ WtO) {
  __shared__ __align__(16) short tl[64 * 72];
  int id = blockIdx.x;
  const float* src; short* dst; int ldS, ldD, k0, n0;
  if (id < 72) { int tk = id / 3, tn = id % 3; src = Wq; dst = Wt;  ldS = 192; ldD = 1536; k0 = tk * 64; n0 = tn * 64; }
  else         { id -= 72;                     src = Wo; dst = WtO; ldS = 768; ldD = 64;   k0 = 0;       n0 = id * 64; }
  const int tid = threadIdx.x;
  const int r = tid >> 2, cq = (tid & 3) * 16;
  const float* sp = src + (size_t)(k0 + r) * ldS + n0 + cq;
  float4v v0 = *(const float4v*)(sp);
  float4v v1 = *(const float4v*)(sp + 4);
  float4v v2 = *(const float4v*)(sp + 8);
  float4v v3 = *(const float4v*)(sp + 12);
  short8 s0, s1;
#pragma unroll
  for (int i = 0; i < 4; ++i) {
    s0[i] = (short)f2bf(v0[i]); s0[i + 4] = (short)f2bf(v1[i]);
    s1[i] = (short)f2bf(v2[i]); s1[i + 4] = (short)f2bf(v3[i]);
  }
  *(short8*)(tl + r * 72 + cq) = s0;
  *(short8*)(tl + r * 72 + cq + 8) = s1;
  __syncthreads();
  short8 o0, o1;
#pragma unroll
  for (int j = 0; j < 8; ++j) {
    o0[j] = tl[(cq + j) * 72 + r];
    o1[j] = tl[(cq + 8 + j) * 72 + r];
  }
  short* dp = dst + (size_t)(n0 + r) * ldD + k0 + cq;
  *(short8*)(dp) = o0;
  *(short8*)(dp + 8) = o1;
}

// ---------------------------------------------------------------------------
// k_qkv: qkv = x @ W_qkv + b, bf16 out. Also emits Vt (V transposed per batch).
// 256 blocks x 256 thr (4 waves). Block = 64 rows x 192 cols. Wave = 64r x 48c.
// x staged f32->bf16 via double-buffered LDS; W-frags direct from L2 (Wt bf16).
// ---------------------------------------------------------------------------
__global__ __launch_bounds__(256) void k_qkv(
    const float* __restrict__ x, const short* __restrict__ Wt,
    const float* __restrict__ bq, short* __restrict__ qkv,
    short* __restrict__ Vt) {
  __shared__ __align__(16) short xl[2][64 * 72];
  const int tid = threadIdx.x;
  const int w = tid >> 6, lane = tid & 63, lo = lane & 15, hi = lane >> 4;
  const int m0 = blockIdx.x * 64;
  const int cb = w * 48;

  float4v acc[4][3];
#pragma unroll
  for (int r = 0; r < 4; ++r)
#pragma unroll
    for (int c = 0; c < 3; ++c) acc[r][c] = (float4v)0.0f;

  const int xr = tid >> 2, xc = (tid & 3) * 16;
  const float* xrow = x + (size_t)(m0 + xr) * 1536 + xc;
  short* xlw0 = &xl[0][xr * 72 + xc];
  short* xlw1 = &xl[1][xr * 72 + xc];

  // prologue: stage k-step 0 into buf0, load W-frags for step 0
  float4v xv0 = *(const float4v*)(xrow + 0);
  float4v xv1 = *(const float4v*)(xrow + 4);
  float4v xv2 = *(const float4v*)(xrow + 8);
  float4v xv3 = *(const float4v*)(xrow + 12);
  short8 bcur[3][2];
#pragma unroll
  for (int c = 0; c < 3; ++c)
#pragma unroll
    for (int ks = 0; ks < 2; ++ks)
      bcur[c][ks] = ldg8(Wt + (size_t)(cb + c * 16 + lo) * 1536 + ks * 32 + hi * 8);
  {
    short8 s0, s1;
#pragma unroll
    for (int i = 0; i < 4; ++i) {
      s0[i] = (short)f2bf(xv0[i]); s0[i + 4] = (short)f2bf(xv1[i]);
      s1[i] = (short)f2bf(xv2[i]); s1[i + 4] = (short)f2bf(xv3[i]);
    }
    *(short8*)(xlw0) = s0; *(short8*)(xlw0 + 8) = s1;
  }
  __syncthreads();

  for (int kk = 0; kk < 24; ++kk) {
    const int cur = kk & 1;
    short8 bnxt[3][2];
    if (kk < 23) {  // issue next-step loads early; latency hides under MFMA
      const int k1 = (kk + 1) * 64;
      xv0 = *(const float4v*)(xrow + k1 + 0);
      xv1 = *(const float4v*)(xrow + k1 + 4);
      xv2 = *(const float4v*)(xrow + k1 + 8);
      xv3 = *(const float4v*)(xrow + k1 + 12);
#pragma unroll
      for (int c = 0; c < 3; ++c)
#pragma unroll
        for (int ks = 0; ks < 2; ++ks)
          bnxt[c][ks] = ldg8(Wt + (size_t)(cb + c * 16 + lo) * 1536 + k1 + ks * 32 + hi * 8);
    }
    const short* xb = &xl[cur][0];
#pragma unroll
    for (int r = 0; r < 4; ++r) {
      short8 a0 = *(const short8*)(xb + (r * 16 + lo) * 72 + hi * 8);
      short8 a1 = *(const short8*)(xb + (r * 16 + lo) * 72 + 32 + hi * 8);
#pragma unroll
      for (int c = 0; c < 3; ++c) {
        acc[r][c] = MFMA16(a0, bcur[c][0], acc[r][c]);
        acc[r][c] = MFMA16(a1, bcur[c][1], acc[r][c]);
      }
    }
    if (kk < 23) {
      short8 s0, s1;
#pragma unroll
      for (int i = 0; i < 4; ++i) {
        s0[i] = (short)f2bf(xv0[i]); s0[i + 4] = (short)f2bf(xv1[i]);
        s1[i] = (short)f2bf(xv2[i]); s1[i + 4] = (short)f2bf(xv3[i]);
      }
      short* dst = cur ? xlw0 : xlw1;
      *(short8*)(dst) = s0; *(short8*)(dst + 8) = s1;
#pragma unroll
      for (int c = 0; c < 3; ++c) { bcur[c][0] = bnxt[c][0]; bcur[c][1] = bnxt[c][1]; }
    }
    __syncthreads();
  }

  // epilogue: bias, store qkv bf16; route v-columns (128..191) into LDS
  float bb[3];
#pragma unroll
  for (int c = 0; c < 3; ++c) bb[c] = bq[cb + c * 16 + lo];

  short* vbuf = &xl[0][0];  // [64 keys][72 pad], d = 0..63
#pragma unroll
  for (int r = 0; r < 4; ++r)
#pragma unroll
    for (int c = 0; c < 3; ++c) {
      const int colb = cb + c * 16;
#pragma unroll
      for (int j = 0; j < 4; ++j) {
        float vv = acc[r][c][j] + bb[c];
        unsigned short u = f2bf(vv);
        qkv[(size_t)(m0 + r * 16 + hi * 4 + j) * 192 + colb + lo] = (short)u;
        if (colb >= 128)
          vbuf[(r * 16 + hi * 4 + j) * 72 + (colb - 128) + lo] = (short)u;
      }
    }
  __syncthreads();

  // transpose-out Vt[b][d][key]
  const int dr = tid >> 2, kq = (tid & 3) * 16;
  short8 o0, o1;
#pragma unroll
  for (int j = 0; j < 8; ++j) {
    o0[j] = vbuf[(kq + j) * 72 + dr];
    o1[j] = vbuf[(kq + 8 + j) * 72 + dr];
  }
  const int b = m0 >> 11, key0 = m0 & 2047;
  short* vp = Vt + (size_t)(b * 64 + dr) * 2048 + key0 + kq;
  *(short8*)(vp) = o0;
  *(short8*)(vp + 8) = o1;
}

// ---------------------------------------------------------------------------
// k_attn: flash attention. 256 blocks x 256 thr; each wave owns 16 q-rows,
// iterates 2048 keys in KT=64 tiles. P round-trips a wave-private LDS tile
// (same-wave LDS is in-order; no barrier needed).
// ---------------------------------------------------------------------------
__global__ __launch_bounds__(256) void k_attn(
    const short* __restrict__ qkv, const short* __restrict__ Vt,
    short* __restrict__ att) {
  __shared__ __align__(16) short pl[4 * 16 * 72];
  const int tid = threadIdx.x;
  const int w = tid >> 6, lane = tid & 63, lo = lane & 15, hi = lane >> 4;
  const int bidx = blockIdx.x;
  const int b = bidx >> 5;                 // 32 blocks per batch
  const int q0 = (bidx & 31) * 64 + w * 16;
  const size_t g0 = (size_t)b * 2048 + q0;
  short* P = pl + w * (16 * 72);
  const float KSC = 0.18033688011112042f;  // (1/8) * log2(e)

  short8 qf0 = ldg8(qkv + (g0 + lo) * 192 + hi * 8);
  short8 qf1 = ldg8(qkv + (g0 + lo) * 192 + 32 + hi * 8);

  float m[4], l[4];
  float4v accv[4];
#pragma unroll
  for (int j = 0; j < 4; ++j) { m[j] = -1e30f; l[j] = 0.0f; }
#pragma unroll
  for (int d = 0; d < 4; ++d) accv[d] = (float4v)0.0f;

  const short* Kb = qkv + (size_t)b * 2048 * 192 + 64;
  const short* Vb = Vt + (size_t)b * 64 * 2048;

  for (int kt = 0; kt < 32; ++kt) {
    const int kb = kt * 64;
    short8 kf[4][2], vf[4][2];
#pragma unroll
    for (int kg = 0; kg < 4; ++kg) {
      const short* kp = Kb + (size_t)(kb + kg * 16 + lo) * 192 + hi * 8;
      kf[kg][0] = ldg8(kp);
      kf[kg][1] = ldg8(kp + 32);
    }
#pragma unroll
    for (int dc = 0; dc < 4; ++dc) {
      const short* vp = Vb + (size_t)(dc * 16 + lo) * 2048 + kb + hi * 8;
      vf[dc][0] = ldg8(vp);
      vf[dc][1] = ldg8(vp + 32);
    }
    float4v sf[4];
#pragma unroll
    for (int kg = 0; kg < 4; ++kg) {
      sf[kg] = MFMA16(qf0, kf[kg][0], (float4v)0.0f);
      sf[kg] = MFMA16(qf1, kf[kg][1], sf[kg]);
    }
    float ts[4][4];
#pragma unroll
    for (int kg = 0; kg < 4; ++kg)
#pragma unroll
      for (int j = 0; j < 4; ++j) ts[kg][j] = sf[kg][j] * KSC;
    float tm[4];
#pragma unroll
    for (int j = 0; j < 4; ++j)
      tm[j] = fmaxf(fmaxf(ts[0][j], ts[1][j]), fmaxf(ts[2][j], ts[3][j]));
#pragma unroll
    for (int msk = 1; msk <= 8; msk <<= 1)
#pragma unroll
      for (int j = 0; j < 4; ++j)
        tm[j] = fmaxf(tm[j], __shfl_xor(tm[j], msk, 64));
    float alpha[4], rs[4];
#pragma unroll
    for (int j = 0; j < 4; ++j) {
      float mn = fmaxf(m[j], tm[j]);
      alpha[j] = __builtin_amdgcn_exp2f(m[j] - mn);
      m[j] = mn;
      rs[j] = 0.0f;
    }
#pragma unroll
    for (int kg = 0; kg < 4; ++kg)
#pragma unroll
      for (int j = 0; j < 4; ++j) {
        float p = __builtin_amdgcn_exp2f(ts[kg][j] - m[j]);
        P[(hi * 4 + j) * 72 + kg * 16 + lo] = (short)f2bf(p);
        rs[j] += p;
      }
#pragma unroll
    for (int msk = 1; msk <= 8; msk <<= 1)
#pragma unroll
      for (int j = 0; j < 4; ++j)
        rs[j] += __shfl_xor(rs[j], msk, 64);
#pragma unroll
    for (int j = 0; j < 4; ++j) l[j] = l[j] * alpha[j] + rs[j];
#pragma unroll
    for (int dc = 0; dc < 4; ++dc)
#pragma unroll
      for (int j = 0; j < 4; ++j) accv[dc][j] *= alpha[j];
    short8 pa0 = *(const short8*)(P + lo * 72 + hi * 8);
    short8 pa1 = *(const short8*)(P + lo * 72 + 32 + hi * 8);
#pragma unroll
    for (int dc = 0; dc < 4; ++dc) {
      accv[dc] = MFMA16(pa0, vf[dc][0], accv[dc]);
      accv[dc] = MFMA16(pa1, vf[dc][1], accv[dc]);
    }
  }
  float inv[4];
#pragma unroll
  for (int j = 0; j < 4; ++j) inv[j] = 1.0f / l[j];
#pragma unroll
  for (int dc = 0; dc < 4; ++dc)
#pragma unroll
    for (int j = 0; j < 4; ++j)
      att[(g0 + hi * 4 + j) * 64 + dc * 16 + lo] = (short)f2bf(accv[dc][j] * inv[j]);
}

// ---------------------------------------------------------------------------
// k_out: out = att @ W_out + b_out (fp32 out). 256 blocks x 512 thr (8 waves).
// Wave = 32 rows x 192 cols; K=64, operands straight from L2.
// ---------------------------------------------------------------------------
__global__ __launch_bounds__(512) void k_out(
    const short* __restrict__ att, const short* __restrict__ WtO,
    const float* __restrict__ bo, float* __restrict__ out) {
  const int tid = threadIdx.x;
  const int w = tid >> 6, lane = tid & 63, lo = lane & 15, hi = lane >> 4;
  const int wr = w >> 2, wc = (w & 3) * 192;
  const int m0 = blockIdx.x * 64 + wr * 32;

  short8 af[2][2];
#pragma unroll
  for (int rf = 0; rf < 2; ++rf) {
    const short* ap = att + (size_t)(m0 + rf * 16 + lo) * 64 + hi * 8;
    af[rf][0] = ldg8(ap);
    af[rf][1] = ldg8(ap + 32);
  }
  float4v acc[2][12];
#pragma unroll
  for (int rf = 0; rf < 2; ++rf)
#pragma unroll
    for (int c = 0; c < 12; ++c) acc[rf][c] = (float4v)0.0f;

#pragma unroll
  for (int c = 0; c < 12; ++c) {
    const short* bp = WtO + (size_t)(wc + c * 16 + lo) * 64 + hi * 8;
    short8 b0 = ldg8(bp);
    short8 b1 = ldg8(bp + 32);
#pragma unroll
    for (int rf = 0; rf < 2; ++rf) {
      acc[rf][c] = MFMA16(af[rf][0], b0, acc[rf][c]);
      acc[rf][c] = MFMA16(af[rf][1], b1, acc[rf][c]);
    }
  }
#pragma unroll
  for (int c = 0; c < 12; ++c) {
    const float bb = bo[wc + c * 16 + lo];
#pragma unroll
    for (int rf = 0; rf < 2; ++rf)
#pragma unroll
      for (int j = 0; j < 4; ++j)
        out[(size_t)(m0 + rf * 16 + hi * 4 + j) * 768 + wc + c * 16 + lo] =
            acc[rf][c][j] + bb;
  }
}

extern "C" void kernel_launch(void* const* d_in, const int* in_sizes, int n_in,
                              void* d_out, int out_size, void* d_ws, size_t ws_size,
                              hipStream_t stream) {
  (void)in_sizes; (void)n_in; (void)out_size; (void)ws_size;
  const float* x  = (const float*)d_in[0];
  const float* Wq = (const float*)d_in[1];
  const float* bq = (const float*)d_in[2];
  const float* Wo = (const float*)d_in[3];
  const float* bo = (const float*)d_in[4];
  float* out = (float*)d_out;

  char* ws = (char*)d_ws;
  short* qkv = (short*)(ws);
  short* Vt  = (short*)(ws + 6291456);
  short* att = (short*)(ws + 8388608);
  short* Wt  = (short*)(ws + 10485760);
  short* WtO = (short*)(ws + 11075584);

  k_prep<<<84, 256, 0, stream>>>(Wq, Wo, Wt, WtO);
  k_qkv<<<256, 256, 0, stream>>>(x, Wt, bq, qkv, Vt);
  k_attn<<<256, 256, 0, stream>>>(qkv, Vt, att);
  k_out<<<256, 512, 0, stream>>>(att, WtO, bo, out);
}

// Round 2
// 126.110 us; speedup vs baseline: 1.0760x; 1.0760x over previous
//
#include <hip/hip_runtime.h>
#include <hip/hip_bf16.h>

// TinyAttention fused pipeline, bf16 MFMA path. Round 2: split-K flash attn.
// ws layout (bytes):
//   qkv bf16 [16384][192]      @ 0          (6,291,456)
//   Vt  bf16 [8][64][2048]     @ 6,291,456  (2,097,152)
//   att bf16 [16384][64]       @ 8,388,608  (2,097,152)
//   Wt  bf16 [192][1536]       @ 10,485,760 (589,824)
//   WtO bf16 [768][64]         @ 11,075,584 (98,304)
//   accP f32 [S][16384][64]    @ 11,173,888 (S*4,194,304)   (split-K partials)
//   mlP  f32 [S][16384][2]     @ after accP (S*131,072)
// total (S=4) ~28.5 MiB; falls back to S=1 if ws_size too small.

typedef __attribute__((ext_vector_type(8))) short short8;
typedef __attribute__((ext_vector_type(4))) short short4v;
typedef __attribute__((ext_vector_type(4))) float float4v;

#define MFMA16(a, b, c) __builtin_amdgcn_mfma_f32_16x16x32_bf16((a), (b), (c), 0, 0, 0)

static __device__ __forceinline__ unsigned short f2bf(float x) {
  union { float f; unsigned u; } v; v.f = x;
  return (unsigned short)((v.u + 0x7FFFu + ((v.u >> 16) & 1u)) >> 16);
}
static __device__ __forceinline__ short8 ldg8(const short* p) {
  return *(const short8*)p;
}

// ---------------------------------------------------------------------------
// k_prep: W_qkv [1536][192] f32 -> Wt [192][1536] bf16 (blocks 0..71)
//         W_out [64][768]  f32 -> WtO [768][64]  bf16 (blocks 72..83)
// ---------------------------------------------------------------------------
__global__ __launch_bounds__(256) void k_prep(
    const float* __restrict__ Wq, const float* __restrict__ Wo,
    short* __restrict__ Wt, short* __restrict__ WtO) {
  __shared__ __align__(16) short tl[64 * 72];
  int id = blockIdx.x;
  const float* src; short* dst; int ldS, ldD, k0, n0;
  if (id < 72) { int tk = id / 3, tn = id % 3; src = Wq; dst = Wt;  ldS = 192; ldD = 1536; k0 = tk * 64; n0 = tn * 64; }
  else         { id -= 72;                     src = Wo; dst = WtO; ldS = 768; ldD = 64;   k0 = 0;       n0 = id * 64; }
  const int tid = threadIdx.x;
  const int r = tid >> 2, cq = (tid & 3) * 16;
  const float* sp = src + (size_t)(k0 + r) * ldS + n0 + cq;
  float4v v0 = *(const float4v*)(sp);
  float4v v1 = *(const float4v*)(sp + 4);
  float4v v2 = *(const float4v*)(sp + 8);
  float4v v3 = *(const float4v*)(sp + 12);
  short8 s0, s1;
#pragma unroll
  for (int i = 0; i < 4; ++i) {
    s0[i] = (short)f2bf(v0[i]); s0[i + 4] = (short)f2bf(v1[i]);
    s1[i] = (short)f2bf(v2[i]); s1[i + 4] = (short)f2bf(v3[i]);
  }
  *(short8*)(tl + r * 72 + cq) = s0;
  *(short8*)(tl + r * 72 + cq + 8) = s1;
  __syncthreads();
  short8 o0, o1;
#pragma unroll
  for (int j = 0; j < 8; ++j) {
    o0[j] = tl[(cq + j) * 72 + r];
    o1[j] = tl[(cq + 8 + j) * 72 + r];
  }
  short* dp = dst + (size_t)(n0 + r) * ldD + k0 + cq;
  *(short8*)(dp) = o0;
  *(short8*)(dp + 8) = o1;
}

// ---------------------------------------------------------------------------
// k_qkv: qkv = x @ W_qkv + b, bf16 out. Also emits Vt (V transposed per batch).
// 256 blocks x 256 thr (4 waves). Block = 64 rows x 192 cols. Wave = 64r x 48c.
// ---------------------------------------------------------------------------
__global__ __launch_bounds__(256) void k_qkv(
    const float* __restrict__ x, const short* __restrict__ Wt,
    const float* __restrict__ bq, short* __restrict__ qkv,
    short* __restrict__ Vt) {
  __shared__ __align__(16) short xl[2][64 * 72];
  const int tid = threadIdx.x;
  const int w = tid >> 6, lane = tid & 63, lo = lane & 15, hi = lane >> 4;
  const int m0 = blockIdx.x * 64;
  const int cb = w * 48;

  float4v acc[4][3];
#pragma unroll
  for (int r = 0; r < 4; ++r)
#pragma unroll
    for (int c = 0; c < 3; ++c) acc[r][c] = (float4v)0.0f;

  const int xr = tid >> 2, xc = (tid & 3) * 16;
  const float* xrow = x + (size_t)(m0 + xr) * 1536 + xc;
  short* xlw0 = &xl[0][xr * 72 + xc];
  short* xlw1 = &xl[1][xr * 72 + xc];

  float4v xv0 = *(const float4v*)(xrow + 0);
  float4v xv1 = *(const float4v*)(xrow + 4);
  float4v xv2 = *(const float4v*)(xrow + 8);
  float4v xv3 = *(const float4v*)(xrow + 12);
  short8 bcur[3][2];
#pragma unroll
  for (int c = 0; c < 3; ++c)
#pragma unroll
    for (int ks = 0; ks < 2; ++ks)
      bcur[c][ks] = ldg8(Wt + (size_t)(cb + c * 16 + lo) * 1536 + ks * 32 + hi * 8);
  {
    short8 s0, s1;
#pragma unroll
    for (int i = 0; i < 4; ++i) {
      s0[i] = (short)f2bf(xv0[i]); s0[i + 4] = (short)f2bf(xv1[i]);
      s1[i] = (short)f2bf(xv2[i]); s1[i + 4] = (short)f2bf(xv3[i]);
    }
    *(short8*)(xlw0) = s0; *(short8*)(xlw0 + 8) = s1;
  }
  __syncthreads();

  for (int kk = 0; kk < 24; ++kk) {
    const int cur = kk & 1;
    short8 bnxt[3][2];
    if (kk < 23) {
      const int k1 = (kk + 1) * 64;
      xv0 = *(const float4v*)(xrow + k1 + 0);
      xv1 = *(const float4v*)(xrow + k1 + 4);
      xv2 = *(const float4v*)(xrow + k1 + 8);
      xv3 = *(const float4v*)(xrow + k1 + 12);
#pragma unroll
      for (int c = 0; c < 3; ++c)
#pragma unroll
        for (int ks = 0; ks < 2; ++ks)
          bnxt[c][ks] = ldg8(Wt + (size_t)(cb + c * 16 + lo) * 1536 + k1 + ks * 32 + hi * 8);
    }
    const short* xb = &xl[cur][0];
#pragma unroll
    for (int r = 0; r < 4; ++r) {
      short8 a0 = *(const short8*)(xb + (r * 16 + lo) * 72 + hi * 8);
      short8 a1 = *(const short8*)(xb + (r * 16 + lo) * 72 + 32 + hi * 8);
#pragma unroll
      for (int c = 0; c < 3; ++c) {
        acc[r][c] = MFMA16(a0, bcur[c][0], acc[r][c]);
        acc[r][c] = MFMA16(a1, bcur[c][1], acc[r][c]);
      }
    }
    if (kk < 23) {
      short8 s0, s1;
#pragma unroll
      for (int i = 0; i < 4; ++i) {
        s0[i] = (short)f2bf(xv0[i]); s0[i + 4] = (short)f2bf(xv1[i]);
        s1[i] = (short)f2bf(xv2[i]); s1[i + 4] = (short)f2bf(xv3[i]);
      }
      short* dst = cur ? xlw0 : xlw1;
      *(short8*)(dst) = s0; *(short8*)(dst + 8) = s1;
#pragma unroll
      for (int c = 0; c < 3; ++c) { bcur[c][0] = bnxt[c][0]; bcur[c][1] = bnxt[c][1]; }
    }
    __syncthreads();
  }

  float bb[3];
#pragma unroll
  for (int c = 0; c < 3; ++c) bb[c] = bq[cb + c * 16 + lo];

  short* vbuf = &xl[0][0];
#pragma unroll
  for (int r = 0; r < 4; ++r)
#pragma unroll
    for (int c = 0; c < 3; ++c) {
      const int colb = cb + c * 16;
#pragma unroll
      for (int j = 0; j < 4; ++j) {
        float vv = acc[r][c][j] + bb[c];
        unsigned short u = f2bf(vv);
        qkv[(size_t)(m0 + r * 16 + hi * 4 + j) * 192 + colb + lo] = (short)u;
        if (colb >= 128)
          vbuf[(r * 16 + hi * 4 + j) * 72 + (colb - 128) + lo] = (short)u;
      }
    }
  __syncthreads();

  const int dr = tid >> 2, kq = (tid & 3) * 16;
  short8 o0, o1;
#pragma unroll
  for (int j = 0; j < 8; ++j) {
    o0[j] = vbuf[(kq + j) * 72 + dr];
    o1[j] = vbuf[(kq + 8 + j) * 72 + dr];
  }
  const int b = m0 >> 11, key0 = m0 & 2047;
  short* vp = Vt + (size_t)(b * 64 + dr) * 2048 + key0 + kq;
  *(short8*)(vp) = o0;
  *(short8*)(vp + 8) = o1;
}

// ---------------------------------------------------------------------------
// k_attn: split-K flash attention. Grid = 256*nsplit blocks x 256 thr.
// Each wave owns 16 q-rows, iterates ktps K-tiles of 64 keys.
// nsplit==1: normalize and write att directly.
// nsplit>1 : write unnormalized O~ (fp32) + (m,l) per row; k_comb merges.
// ---------------------------------------------------------------------------
__global__ __launch_bounds__(256) void k_attn(
    const short* __restrict__ qkv, const short* __restrict__ Vt,
    short* __restrict__ att, float* __restrict__ accP,
    float* __restrict__ mlP, int nsplit, int ktps) {
  __shared__ __align__(16) short pl[4 * 16 * 72];
  const int tid = threadIdx.x;
  const int w = tid >> 6, lane = tid & 63, lo = lane & 15, hi = lane >> 4;
  const int unit = blockIdx.x & 255;
  const int split = blockIdx.x >> 8;
  const int b = unit >> 5;
  const int q0 = (unit & 31) * 64 + w * 16;
  const size_t g0 = (size_t)b * 2048 + q0;
  short* P = pl + w * (16 * 72);
  const float KSC = 0.18033688011112042f;  // (1/8) * log2(e)

  short8 qf0 = ldg8(qkv + (g0 + lo) * 192 + hi * 8);
  short8 qf1 = ldg8(qkv + (g0 + lo) * 192 + 32 + hi * 8);

  float m[4], l[4];
  float4v accv[4];
#pragma unroll
  for (int j = 0; j < 4; ++j) { m[j] = -1e30f; l[j] = 0.0f; }
#pragma unroll
  for (int d = 0; d < 4; ++d) accv[d] = (float4v)0.0f;

  const short* Kb = qkv + (size_t)b * 2048 * 192 + 64;
  const short* Vb = Vt + (size_t)b * 64 * 2048;

  const int kt0 = split * ktps;
  for (int kt = kt0; kt < kt0 + ktps; ++kt) {
    const int kb = kt * 64;
    short8 kf[4][2], vf[4][2];
#pragma unroll
    for (int kg = 0; kg < 4; ++kg) {
      const short* kp = Kb + (size_t)(kb + kg * 16 + lo) * 192 + hi * 8;
      kf[kg][0] = ldg8(kp);
      kf[kg][1] = ldg8(kp + 32);
    }
#pragma unroll
    for (int dc = 0; dc < 4; ++dc) {
      const short* vp = Vb + (size_t)(dc * 16 + lo) * 2048 + kb + hi * 8;
      vf[dc][0] = ldg8(vp);
      vf[dc][1] = ldg8(vp + 32);
    }
    float4v sf[4];
#pragma unroll
    for (int kg = 0; kg < 4; ++kg) {
      sf[kg] = MFMA16(qf0, kf[kg][0], (float4v)0.0f);
      sf[kg] = MFMA16(qf1, kf[kg][1], sf[kg]);
    }
    float ts[4][4];
#pragma unroll
    for (int kg = 0; kg < 4; ++kg)
#pragma unroll
      for (int j = 0; j < 4; ++j) ts[kg][j] = sf[kg][j] * KSC;
    float tm[4];
#pragma unroll
    for (int j = 0; j < 4; ++j)
      tm[j] = fmaxf(fmaxf(ts[0][j], ts[1][j]), fmaxf(ts[2][j], ts[3][j]));
#pragma unroll
    for (int msk = 1; msk <= 8; msk <<= 1)
#pragma unroll
      for (int j = 0; j < 4; ++j)
        tm[j] = fmaxf(tm[j], __shfl_xor(tm[j], msk, 64));
    float alpha[4], rs[4];
#pragma unroll
    for (int j = 0; j < 4; ++j) {
      float mn = fmaxf(m[j], tm[j]);
      alpha[j] = __builtin_amdgcn_exp2f(m[j] - mn);
      m[j] = mn;
      rs[j] = 0.0f;
    }
#pragma unroll
    for (int kg = 0; kg < 4; ++kg)
#pragma unroll
      for (int j = 0; j < 4; ++j) {
        float p = __builtin_amdgcn_exp2f(ts[kg][j] - m[j]);
        P[(hi * 4 + j) * 72 + kg * 16 + lo] = (short)f2bf(p);
        rs[j] += p;
      }
#pragma unroll
    for (int msk = 1; msk <= 8; msk <<= 1)
#pragma unroll
      for (int j = 0; j < 4; ++j)
        rs[j] += __shfl_xor(rs[j], msk, 64);
#pragma unroll
    for (int j = 0; j < 4; ++j) l[j] = l[j] * alpha[j] + rs[j];
#pragma unroll
    for (int dc = 0; dc < 4; ++dc)
#pragma unroll
      for (int j = 0; j < 4; ++j) accv[dc][j] *= alpha[j];
    short8 pa0 = *(const short8*)(P + lo * 72 + hi * 8);
    short8 pa1 = *(const short8*)(P + lo * 72 + 32 + hi * 8);
#pragma unroll
    for (int dc = 0; dc < 4; ++dc) {
      accv[dc] = MFMA16(pa0, vf[dc][0], accv[dc]);
      accv[dc] = MFMA16(pa1, vf[dc][1], accv[dc]);
    }
  }

  if (nsplit == 1) {
    float inv[4];
#pragma unroll
    for (int j = 0; j < 4; ++j) inv[j] = 1.0f / l[j];
#pragma unroll
    for (int dc = 0; dc < 4; ++dc)
#pragma unroll
      for (int j = 0; j < 4; ++j)
        att[(g0 + hi * 4 + j) * 64 + dc * 16 + lo] = (short)f2bf(accv[dc][j] * inv[j]);
  } else {
    const size_t pbase = ((size_t)split * 16384 + g0);
#pragma unroll
    for (int dc = 0; dc < 4; ++dc)
#pragma unroll
      for (int j = 0; j < 4; ++j)
        accP[(pbase + hi * 4 + j) * 64 + dc * 16 + lo] = accv[dc][j];
    if (lo == 0) {
#pragma unroll
      for (int j = 0; j < 4; ++j) {
        mlP[2 * (pbase + hi * 4 + j) + 0] = m[j];
        mlP[2 * (pbase + hi * 4 + j) + 1] = l[j];
      }
    }
  }
}

// ---------------------------------------------------------------------------
// k_comb: merge split-K partials. 1024 blocks x 256 thr; thread = (row, 4 d).
// ---------------------------------------------------------------------------
__global__ __launch_bounds__(256) void k_comb(
    const float* __restrict__ accP, const float* __restrict__ mlP,
    short* __restrict__ att, int nsplit) {
  const int gid = blockIdx.x * 256 + threadIdx.x;
  const int row = gid >> 4;
  const int dq = (gid & 15) * 4;
  float M = -1e30f;
  for (int s = 0; s < nsplit; ++s)
    M = fmaxf(M, mlP[2 * ((size_t)s * 16384 + row)]);
  float L = 0.0f, o0 = 0.0f, o1 = 0.0f, o2 = 0.0f, o3 = 0.0f;
  for (int s = 0; s < nsplit; ++s) {
    const size_t pr = (size_t)s * 16384 + row;
    const float ms = mlP[2 * pr], ls = mlP[2 * pr + 1];
    const float e = __builtin_amdgcn_exp2f(ms - M);
    L += ls * e;
    const float4v a = *(const float4v*)(accP + pr * 64 + dq);
    o0 += a[0] * e; o1 += a[1] * e; o2 += a[2] * e; o3 += a[3] * e;
  }
  const float inv = 1.0f / L;
  short4v r;
  r[0] = (short)f2bf(o0 * inv);
  r[1] = (short)f2bf(o1 * inv);
  r[2] = (short)f2bf(o2 * inv);
  r[3] = (short)f2bf(o3 * inv);
  *(short4v*)(att + (size_t)row * 64 + dq) = r;
}

// ---------------------------------------------------------------------------
// k_out: out = att @ W_out + b_out (fp32 out). 256 blocks x 512 thr (8 waves).
// ---------------------------------------------------------------------------
__global__ __launch_bounds__(512) void k_out(
    const short* __restrict__ att, const short* __restrict__ WtO,
    const float* __restrict__ bo, float* __restrict__ out) {
  const int tid = threadIdx.x;
  const int w = tid >> 6, lane = tid & 63, lo = lane & 15, hi = lane >> 4;
  const int wr = w >> 2, wc = (w & 3) * 192;
  const int m0 = blockIdx.x * 64 + wr * 32;

  short8 af[2][2];
#pragma unroll
  for (int rf = 0; rf < 2; ++rf) {
    const short* ap = att + (size_t)(m0 + rf * 16 + lo) * 64 + hi * 8;
    af[rf][0] = ldg8(ap);
    af[rf][1] = ldg8(ap + 32);
  }
  float4v acc[2][12];
#pragma unroll
  for (int rf = 0; rf < 2; ++rf)
#pragma unroll
    for (int c = 0; c < 12; ++c) acc[rf][c] = (float4v)0.0f;

#pragma unroll
  for (int c = 0; c < 12; ++c) {
    const short* bp = WtO + (size_t)(wc + c * 16 + lo) * 64 + hi * 8;
    short8 b0 = ldg8(bp);
    short8 b1 = ldg8(bp + 32);
#pragma unroll
    for (int rf = 0; rf < 2; ++rf) {
      acc[rf][c] = MFMA16(af[rf][0], b0, acc[rf][c]);
      acc[rf][c] = MFMA16(af[rf][1], b1, acc[rf][c]);
    }
  }
#pragma unroll
  for (int c = 0; c < 12; ++c) {
    const float bb = bo[wc + c * 16 + lo];
#pragma unroll
    for (int rf = 0; rf < 2; ++rf)
#pragma unroll
      for (int j = 0; j < 4; ++j)
        out[(size_t)(m0 + rf * 16 + hi * 4 + j) * 768 + wc + c * 16 + lo] =
            acc[rf][c][j] + bb;
  }
}

extern "C" void kernel_launch(void* const* d_in, const int* in_sizes, int n_in,
                              void* d_out, int out_size, void* d_ws, size_t ws_size,
                              hipStream_t stream) {
  (void)in_sizes; (void)n_in; (void)out_size;
  const float* x  = (const float*)d_in[0];
  const float* Wq = (const float*)d_in[1];
  const float* bq = (const float*)d_in[2];
  const float* Wo = (const float*)d_in[3];
  const float* bo = (const float*)d_in[4];
  float* out = (float*)d_out;

  char* ws = (char*)d_ws;
  short* qkv = (short*)(ws);
  short* Vt  = (short*)(ws + 6291456);
  short* att = (short*)(ws + 8388608);
  short* Wt  = (short*)(ws + 10485760);
  short* WtO = (short*)(ws + 11075584);

  const size_t pbase = 11173888;
  int nsplit = 1;
  if (ws_size >= pbase + 4u * (4194304u + 131072u)) nsplit = 4;
  float* accP = (float*)(ws + pbase);
  float* mlP  = (float*)(ws + pbase + (size_t)nsplit * 4194304u);
  const int ktps = 32 / nsplit;

  k_prep<<<84, 256, 0, stream>>>(Wq, Wo, Wt, WtO);
  k_qkv<<<256, 256, 0, stream>>>(x, Wt, bq, qkv, Vt);
  k_attn<<<256 * nsplit, 256, 0, stream>>>(qkv, Vt, att, accP, mlP, nsplit, ktps);
  if (nsplit > 1)
    k_comb<<<1024, 256, 0, stream>>>(accP, mlP, att, nsplit);
  k_out<<<256, 512, 0, stream>>>(att, WtO, bo, out);
}

// Round 5
// 111.400 us; speedup vs baseline: 1.2181x; 1.1321x over previous
//
#include <hip/hip_runtime.h>
#include <hip/hip_bf16.h>

// TinyAttention fused pipeline, bf16 MFMA path.
// Round 5: all-builtin 32x32x16 flash attn; P exchanged via v_permlane32_swap_b32
// (VALU, interlock-safe) instead of inline-asm MFMA (hazard-prone, r4 NaN).
// ws layout (bytes):
//   qkv bf16 [16384][192]      @ 0          (6,291,456)   q-cols pre-scaled by KSC
//   Vt  bf16 [8][64][2048]     @ 6,291,456  (2,097,152)
//   att bf16 [16384][64]       @ 8,388,608  (2,097,152)
//   Wt  bf16 [192][1536]       @ 10,485,760 (589,824)
//   WtO bf16 [768][64]         @ 11,075,584 (98,304)
//   accP f32 [S][16384][64]    @ 11,173,888 (S*4,194,304)   (split-K partials)
//   lP   f32 [S][16384]        @ after accP (S*65,536)

typedef __attribute__((ext_vector_type(8))) short short8;
typedef __attribute__((ext_vector_type(4))) short short4v;
typedef __attribute__((ext_vector_type(4))) float float4v;
typedef __attribute__((ext_vector_type(16))) float float16v;

#define MFMA16(a, b, c) __builtin_amdgcn_mfma_f32_16x16x32_bf16((a), (b), (c), 0, 0, 0)
#define MFMA32(a, b, c) __builtin_amdgcn_mfma_f32_32x32x16_bf16((a), (b), (c), 0, 0, 0)

// v_permlane32_swap_b32 a, b:  a[32+i] <-> b[i]  (VALU cross-lane, no DS)
static __device__ __forceinline__ void plswap(unsigned& a, unsigned& b) {
  asm("v_permlane32_swap_b32 %0, %1" : "+v"(a), "+v"(b));
}

static __device__ __forceinline__ unsigned short f2bf(float x) {
  union { float f; unsigned u; } v; v.f = x;
  return (unsigned short)((v.u + 0x7FFFu + ((v.u >> 16) & 1u)) >> 16);
}
static __device__ __forceinline__ short8 ldg8(const short* p) {
  return *(const short8*)p;
}

// ---------------------------------------------------------------------------
// k_prep: W_qkv [1536][192] f32 -> Wt [192][1536] bf16 (blocks 0..71)
//         W_out [64][768]  f32 -> WtO [768][64]  bf16 (blocks 72..83)
// ---------------------------------------------------------------------------
__global__ __launch_bounds__(256) void k_prep(
    const float* __restrict__ Wq, const float* __restrict__ Wo,
    short* __restrict__ Wt, short* __restrict__ WtO) {
  __shared__ __align__(16) short tl[64 * 72];
  int id = blockIdx.x;
  const float* src; short* dst; int ldS, ldD, k0, n0;
  if (id < 72) { int tk = id / 3, tn = id % 3; src = Wq; dst = Wt;  ldS = 192; ldD = 1536; k0 = tk * 64; n0 = tn * 64; }
  else         { id -= 72;                     src = Wo; dst = WtO; ldS = 768; ldD = 64;   k0 = 0;       n0 = id * 64; }
  const int tid = threadIdx.x;
  const int r = tid >> 2, cq = (tid & 3) * 16;
  const float* sp = src + (size_t)(k0 + r) * ldS + n0 + cq;
  float4v v0 = *(const float4v*)(sp);
  float4v v1 = *(const float4v*)(sp + 4);
  float4v v2 = *(const float4v*)(sp + 8);
  float4v v3 = *(const float4v*)(sp + 12);
  short8 s0, s1;
#pragma unroll
  for (int i = 0; i < 4; ++i) {
    s0[i] = (short)f2bf(v0[i]); s0[i + 4] = (short)f2bf(v1[i]);
    s1[i] = (short)f2bf(v2[i]); s1[i + 4] = (short)f2bf(v3[i]);
  }
  *(short8*)(tl + r * 72 + cq) = s0;
  *(short8*)(tl + r * 72 + cq + 8) = s1;
  __syncthreads();
  short8 o0, o1;
#pragma unroll
  for (int j = 0; j < 8; ++j) {
    o0[j] = tl[(cq + j) * 72 + r];
    o1[j] = tl[(cq + 8 + j) * 72 + r];
  }
  short* dp = dst + (size_t)(n0 + r) * ldD + k0 + cq;
  *(short8*)(dp) = o0;
  *(short8*)(dp + 8) = o1;
}

// ---------------------------------------------------------------------------
// k_qkv: qkv = x @ W_qkv + b, bf16 out. q-columns (<64) pre-scaled by KSC.
// Also emits Vt (V transposed per batch). 256 blocks x 256 thr (4 waves).
// ---------------------------------------------------------------------------
__global__ __launch_bounds__(256) void k_qkv(
    const float* __restrict__ x, const short* __restrict__ Wt,
    const float* __restrict__ bq, short* __restrict__ qkv,
    short* __restrict__ Vt) {
  __shared__ __align__(16) short xl[2][64 * 72];
  const int tid = threadIdx.x;
  const int w = tid >> 6, lane = tid & 63, lo = lane & 15, hi = lane >> 4;
  const int m0 = blockIdx.x * 64;
  const int cb = w * 48;
  const float KSC = 0.18033688011112042f;  // (1/8) * log2(e)

  float4v acc[4][3];
#pragma unroll
  for (int r = 0; r < 4; ++r)
#pragma unroll
    for (int c = 0; c < 3; ++c) acc[r][c] = (float4v)0.0f;

  const int xr = tid >> 2, xc = (tid & 3) * 16;
  const float* xrow = x + (size_t)(m0 + xr) * 1536 + xc;
  short* xlw0 = &xl[0][xr * 72 + xc];
  short* xlw1 = &xl[1][xr * 72 + xc];

  float4v xv0 = *(const float4v*)(xrow + 0);
  float4v xv1 = *(const float4v*)(xrow + 4);
  float4v xv2 = *(const float4v*)(xrow + 8);
  float4v xv3 = *(const float4v*)(xrow + 12);
  short8 bcur[3][2];
#pragma unroll
  for (int c = 0; c < 3; ++c)
#pragma unroll
    for (int ks = 0; ks < 2; ++ks)
      bcur[c][ks] = ldg8(Wt + (size_t)(cb + c * 16 + lo) * 1536 + ks * 32 + hi * 8);
  {
    short8 s0, s1;
#pragma unroll
    for (int i = 0; i < 4; ++i) {
      s0[i] = (short)f2bf(xv0[i]); s0[i + 4] = (short)f2bf(xv1[i]);
      s1[i] = (short)f2bf(xv2[i]); s1[i + 4] = (short)f2bf(xv3[i]);
    }
    *(short8*)(xlw0) = s0; *(short8*)(xlw0 + 8) = s1;
  }
  __syncthreads();

  for (int kk = 0; kk < 24; ++kk) {
    const int cur = kk & 1;
    short8 bnxt[3][2];
    if (kk < 23) {
      const int k1 = (kk + 1) * 64;
      xv0 = *(const float4v*)(xrow + k1 + 0);
      xv1 = *(const float4v*)(xrow + k1 + 4);
      xv2 = *(const float4v*)(xrow + k1 + 8);
      xv3 = *(const float4v*)(xrow + k1 + 12);
#pragma unroll
      for (int c = 0; c < 3; ++c)
#pragma unroll
        for (int ks = 0; ks < 2; ++ks)
          bnxt[c][ks] = ldg8(Wt + (size_t)(cb + c * 16 + lo) * 1536 + k1 + ks * 32 + hi * 8);
    }
    const short* xb = &xl[cur][0];
#pragma unroll
    for (int r = 0; r < 4; ++r) {
      short8 a0 = *(const short8*)(xb + (r * 16 + lo) * 72 + hi * 8);
      short8 a1 = *(const short8*)(xb + (r * 16 + lo) * 72 + 32 + hi * 8);
#pragma unroll
      for (int c = 0; c < 3; ++c) {
        acc[r][c] = MFMA16(a0, bcur[c][0], acc[r][c]);
        acc[r][c] = MFMA16(a1, bcur[c][1], acc[r][c]);
      }
    }
    if (kk < 23) {
      short8 s0, s1;
#pragma unroll
      for (int i = 0; i < 4; ++i) {
        s0[i] = (short)f2bf(xv0[i]); s0[i + 4] = (short)f2bf(xv1[i]);
        s1[i] = (short)f2bf(xv2[i]); s1[i + 4] = (short)f2bf(xv3[i]);
      }
      short* dst = cur ? xlw0 : xlw1;
      *(short8*)(dst) = s0; *(short8*)(dst + 8) = s1;
#pragma unroll
      for (int c = 0; c < 3; ++c) { bcur[c][0] = bnxt[c][0]; bcur[c][1] = bnxt[c][1]; }
    }
    __syncthreads();
  }

  float bb[3];
#pragma unroll
  for (int c = 0; c < 3; ++c) bb[c] = bq[cb + c * 16 + lo];

  short* vbuf = &xl[0][0];
#pragma unroll
  for (int r = 0; r < 4; ++r)
#pragma unroll
    for (int c = 0; c < 3; ++c) {
      const int colb = cb + c * 16;
#pragma unroll
      for (int j = 0; j < 4; ++j) {
        float vv = acc[r][c][j] + bb[c];
        if (colb < 64) vv *= KSC;  // q-columns: fold softmax scale (exp2 domain)
        unsigned short u = f2bf(vv);
        qkv[(size_t)(m0 + r * 16 + hi * 4 + j) * 192 + colb + lo] = (short)u;
        if (colb >= 128)
          vbuf[(r * 16 + hi * 4 + j) * 72 + (colb - 128) + lo] = (short)u;
      }
    }
  __syncthreads();

  const int dr = tid >> 2, kq = (tid & 3) * 16;
  short8 o0, o1;
#pragma unroll
  for (int j = 0; j < 8; ++j) {
    o0[j] = vbuf[(kq + j) * 72 + dr];
    o1[j] = vbuf[(kq + 8 + j) * 72 + dr];
  }
  const int b = m0 >> 11, key0 = m0 & 2047;
  short* vp = Vt + (size_t)(b * 64 + dr) * 2048 + key0 + kq;
  *(short8*)(vp) = o0;
  *(short8*)(vp + 8) = o1;
}

// ---------------------------------------------------------------------------
// k_attn: all-builtin split-K flash attn, 32x32x16 tiles, no LDS.
// Grid = 128*nsplit blocks x 256 thr (4 waves); wave owns 32 q rows.
// Swapped QK: D[key][q], col=q=lane&31 -> softmax lane-local, no max-track.
// P-exchange for PV B-frag: 4x v_permlane32_swap_b32 per 32-key subtile.
// ---------------------------------------------------------------------------
__global__ __launch_bounds__(256) void k_attn(
    const short* __restrict__ qkv, const short* __restrict__ Vt,
    short* __restrict__ att, float* __restrict__ accP,
    float* __restrict__ lP, int nsplit, int ktps) {
  const int tid = threadIdx.x;
  const int w = tid >> 6, lane = tid & 63;
  const int c = lane & 31, h = lane >> 5;
  const int unit = blockIdx.x & 127;
  const int split = blockIdx.x >> 7;
  const int b = unit >> 4;                    // 16 blocks per batch
  const int q0 = (unit & 15) * 128 + w * 32;
  const size_t g0 = (size_t)b * 2048 + q0;

  // Q (B-operand): col=q=c, k=8h+e -> d=16i+8h+e. Pre-scaled by KSC in k_qkv.
  short8 qf[4];
#pragma unroll
  for (int i = 0; i < 4; ++i)
    qf[i] = ldg8(qkv + (g0 + c) * 192 + i * 16 + h * 8);

  float lp = 0.0f;
  float16v acc0 = (float16v)0.0f;   // O^T d 0..31
  float16v acc1 = (float16v)0.0f;   // O^T d 32..63

  const int kb0 = split * ktps * 64;
  // K rows (A-operand): row=key offset=c, k=8h+e -> d
  const short* kp = qkv + ((size_t)b * 2048 + kb0 + c) * 192 + 64 + h * 8;
  // V^T rows (A-operand): row=d (dc*32+c), k=8h+e -> key
  const short* vr0 = Vt + ((size_t)b * 64 + c) * 2048 + kb0 + h * 8;
  const short* vr1 = Vt + ((size_t)b * 64 + 32 + c) * 2048 + kb0 + h * 8;

  for (int kt = 0; kt < ktps; ++kt) {
#pragma unroll
    for (int s = 0; s < 2; ++s) {
      const int ko = kt * 64 + s * 32;
      const short* kps = kp + (size_t)ko * 192;
      short8 kf0 = ldg8(kps);
      short8 kf1 = ldg8(kps + 16);
      short8 kf2 = ldg8(kps + 32);
      short8 kf3 = ldg8(kps + 48);
      float16v sf = (float16v)0.0f;
      sf = MFMA32(kf0, qf[0], sf);
      sf = MFMA32(kf1, qf[1], sf);
      sf = MFMA32(kf2, qf[2], sf);
      sf = MFMA32(kf3, qf[3], sf);
      // p = exp2(sf) (already in exp2 domain); truncate to bf16; l from
      // the truncated values so P/l bias cancels in O/l.
      unsigned wpk[8];
#pragma unroll
      for (int m = 0; m < 8; ++m) {
        float p0 = __builtin_amdgcn_exp2f(sf[2 * m]);
        float p1 = __builtin_amdgcn_exp2f(sf[2 * m + 1]);
        unsigned u0 = __builtin_bit_cast(unsigned, p0) & 0xFFFF0000u;
        unsigned u1 = __builtin_bit_cast(unsigned, p1) & 0xFFFF0000u;
        lp += __builtin_bit_cast(float, u0) + __builtin_bit_cast(float, u1);
        wpk[m] = (u0 >> 16) | u1;
      }
      // Exchange halves: after swap, wpk[0..3] = B-frag words of key-half T0,
      // wpk[4..7] = key-half T1 (derivation in round notes).
      plswap(wpk[0], wpk[2]);
      plswap(wpk[1], wpk[3]);
      plswap(wpk[4], wpk[6]);
      plswap(wpk[5], wpk[7]);
      union { unsigned u[4]; short8 s8; } bt0, bt1;
      bt0.u[0] = wpk[0]; bt0.u[1] = wpk[1]; bt0.u[2] = wpk[2]; bt0.u[3] = wpk[3];
      bt1.u[0] = wpk[4]; bt1.u[1] = wpk[5]; bt1.u[2] = wpk[6]; bt1.u[3] = wpk[7];

      short8 vf00 = ldg8(vr0 + ko);        // dc=0, keys T0
      short8 vf01 = ldg8(vr0 + ko + 16);   // dc=0, keys T1
      short8 vf10 = ldg8(vr1 + ko);        // dc=1, keys T0
      short8 vf11 = ldg8(vr1 + ko + 16);   // dc=1, keys T1
      acc0 = MFMA32(vf00, bt0.s8, acc0);
      acc0 = MFMA32(vf01, bt1.s8, acc0);
      acc1 = MFMA32(vf10, bt0.s8, acc1);
      acc1 = MFMA32(vf11, bt1.s8, acc1);
    }
  }

  // combine per-half partial row sums (lanes c and c+32)
  lp += __shfl_xor(lp, 32, 64);

  if (nsplit == 1) {
    const float inv = 1.0f / lp;
#pragma unroll
    for (int g = 0; g < 4; ++g) {
      short4v r0, r1;
#pragma unroll
      for (int r = 0; r < 4; ++r) {
        r0[r] = (short)f2bf(acc0[4 * g + r] * inv);
        r1[r] = (short)f2bf(acc1[4 * g + r] * inv);
      }
      *(short4v*)(att + (g0 + c) * 64 + 8 * g + 4 * h) = r0;
      *(short4v*)(att + (g0 + c) * 64 + 32 + 8 * g + 4 * h) = r1;
    }
  } else {
    const size_t prow = (size_t)split * 16384 + g0 + c;
#pragma unroll
    for (int g = 0; g < 4; ++g) {
      float4v a0, a1;
#pragma unroll
      for (int r = 0; r < 4; ++r) { a0[r] = acc0[4 * g + r]; a1[r] = acc1[4 * g + r]; }
      *(float4v*)(accP + prow * 64 + 8 * g + 4 * h) = a0;
      *(float4v*)(accP + prow * 64 + 32 + 8 * g + 4 * h) = a1;
    }
    if (h == 0) lP[prow] = lp;
  }
}

// ---------------------------------------------------------------------------
// k_comb: merge split-K partials (plain sums, no max-track). 1024 blks x 256.
// ---------------------------------------------------------------------------
__global__ __launch_bounds__(256) void k_comb(
    const float* __restrict__ accP, const float* __restrict__ lP,
    short* __restrict__ att, int nsplit) {
  const int gid = blockIdx.x * 256 + threadIdx.x;
  const int row = gid >> 4;
  const int dq = (gid & 15) * 4;
  float L = 0.0f;
  float4v o = (float4v)0.0f;
  for (int s = 0; s < nsplit; ++s) {
    const size_t pr = (size_t)s * 16384 + row;
    L += lP[pr];
    const float4v a = *(const float4v*)(accP + pr * 64 + dq);
    o += a;
  }
  const float inv = 1.0f / L;
  short4v r;
#pragma unroll
  for (int j = 0; j < 4; ++j) r[j] = (short)f2bf(o[j] * inv);
  *(short4v*)(att + (size_t)row * 64 + dq) = r;
}

// ---------------------------------------------------------------------------
// k_out: out = att @ W_out + b_out (fp32 out). 256 blocks x 512 thr (8 waves).
// ---------------------------------------------------------------------------
__global__ __launch_bounds__(512) void k_out(
    const short* __restrict__ att, const short* __restrict__ WtO,
    const float* __restrict__ bo, float* __restrict__ out) {
  const int tid = threadIdx.x;
  const int w = tid >> 6, lane = tid & 63, lo = lane & 15, hi = lane >> 4;
  const int wr = w >> 2, wc = (w & 3) * 192;
  const int m0 = blockIdx.x * 64 + wr * 32;

  short8 af[2][2];
#pragma unroll
  for (int rf = 0; rf < 2; ++rf) {
    const short* ap = att + (size_t)(m0 + rf * 16 + lo) * 64 + hi * 8;
    af[rf][0] = ldg8(ap);
    af[rf][1] = ldg8(ap + 32);
  }
  float4v acc[2][12];
#pragma unroll
  for (int rf = 0; rf < 2; ++rf)
#pragma unroll
    for (int c = 0; c < 12; ++c) acc[rf][c] = (float4v)0.0f;

#pragma unroll
  for (int c = 0; c < 12; ++c) {
    const short* bp = WtO + (size_t)(wc + c * 16 + lo) * 64 + hi * 8;
    short8 b0 = ldg8(bp);
    short8 b1 = ldg8(bp + 32);
#pragma unroll
    for (int rf = 0; rf < 2; ++rf) {
      acc[rf][c] = MFMA16(af[rf][0], b0, acc[rf][c]);
      acc[rf][c] = MFMA16(af[rf][1], b1, acc[rf][c]);
    }
  }
#pragma unroll
  for (int c = 0; c < 12; ++c) {
    const float bb = bo[wc + c * 16 + lo];
#pragma unroll
    for (int rf = 0; rf < 2; ++rf)
#pragma unroll
      for (int j = 0; j < 4; ++j)
        out[(size_t)(m0 + rf * 16 + hi * 4 + j) * 768 + wc + c * 16 + lo] =
            acc[rf][c][j] + bb;
  }
}

extern "C" void kernel_launch(void* const* d_in, const int* in_sizes, int n_in,
                              void* d_out, int out_size, void* d_ws, size_t ws_size,
                              hipStream_t stream) {
  (void)in_sizes; (void)n_in; (void)out_size;
  const float* x  = (const float*)d_in[0];
  const float* Wq = (const float*)d_in[1];
  const float* bq = (const float*)d_in[2];
  const float* Wo = (const float*)d_in[3];
  const float* bo = (const float*)d_in[4];
  float* out = (float*)d_out;

  char* ws = (char*)d_ws;
  short* qkv = (short*)(ws);
  short* Vt  = (short*)(ws + 6291456);
  short* att = (short*)(ws + 8388608);
  short* Wt  = (short*)(ws + 10485760);
  short* WtO = (short*)(ws + 11075584);

  const size_t pbase = 11173888;
  int nsplit = 1;
  if (ws_size >= pbase + 8u * (4194304u + 65536u)) nsplit = 8;
  else if (ws_size >= pbase + 4u * (4194304u + 65536u)) nsplit = 4;
  float* accP = (float*)(ws + pbase);
  float* lP   = (float*)(ws + pbase + (size_t)nsplit * 4194304u);
  const int ktps = 32 / nsplit;

  k_prep<<<84, 256, 0, stream>>>(Wq, Wo, Wt, WtO);
  k_qkv<<<256, 256, 0, stream>>>(x, Wt, bq, qkv, Vt);
  k_attn<<<128 * nsplit, 256, 0, stream>>>(qkv, Vt, att, accP, lP, nsplit, ktps);
  if (nsplit > 1)
    k_comb<<<1024, 256, 0, stream>>>(accP, lP, att, nsplit);
  k_out<<<256, 512, 0, stream>>>(att, WtO, bo, out);
}

// Round 6
// 94.162 us; speedup vs baseline: 1.4411x; 1.1831x over previous
//
#include <hip/hip_runtime.h>
#include <hip/hip_bf16.h>

// TinyAttention fused pipeline, bf16 MFMA path.
// Round 6: fragment-native intermediate layouts -> every k_attn load is a
// fully-coalesced 1KB global_load_dwordx4 (base + lane*8). Compute identical
// to round 5 (swapped QK, lane-local no-max softmax, permlane32 P-exchange).
// ws layout (bytes):
//   Qf  bf16 [8][64][4][2][32][8] @ 0         (2,097,152)  (q-cols pre-scaled)
//   Kf  bf16 [8][64][4][2][32][8] @ 2,097,152 (2,097,152)
//   Vf  bf16 [8][64][2][2][2][32][8] @ 4,194,304 (2,097,152)
//   att bf16 [16384][64]          @ 6,291,456 (2,097,152)
//   Wt  bf16 [192][1536]          @ 8,388,608 (589,824)
//   WtO bf16 [768][64]            @ 8,978,432 (98,304)
//   accP f32 [S][16384][64]       @ 9,076,736 (S*4,194,304)
//   lP   f32 [S][16384]           @ after accP (S*65,536)

typedef __attribute__((ext_vector_type(8))) short short8;
typedef __attribute__((ext_vector_type(4))) short short4v;
typedef __attribute__((ext_vector_type(4))) float float4v;
typedef __attribute__((ext_vector_type(16))) float float16v;

#define MFMA16(a, b, c) __builtin_amdgcn_mfma_f32_16x16x32_bf16((a), (b), (c), 0, 0, 0)
#define MFMA32(a, b, c) __builtin_amdgcn_mfma_f32_32x32x16_bf16((a), (b), (c), 0, 0, 0)

// v_permlane32_swap_b32 a, b:  a[32+i] <-> b[i]  (VALU cross-lane, no DS)
static __device__ __forceinline__ void plswap(unsigned& a, unsigned& b) {
  asm("v_permlane32_swap_b32 %0, %1" : "+v"(a), "+v"(b));
}

static __device__ __forceinline__ unsigned short f2bf(float x) {
  union { float f; unsigned u; } v; v.f = x;
  return (unsigned short)((v.u + 0x7FFFu + ((v.u >> 16) & 1u)) >> 16);
}
static __device__ __forceinline__ short8 ldg8(const short* p) {
  return *(const short8*)p;
}

// ---------------------------------------------------------------------------
// k_prep: W_qkv [1536][192] f32 -> Wt [192][1536] bf16 (blocks 0..71)
//         W_out [64][768]  f32 -> WtO [768][64]  bf16 (blocks 72..83)
// ---------------------------------------------------------------------------
__global__ __launch_bounds__(256) void k_prep(
    const float* __restrict__ Wq, const float* __restrict__ Wo,
    short* __restrict__ Wt, short* __restrict__ WtO) {
  __shared__ __align__(16) short tl[64 * 72];
  int id = blockIdx.x;
  const float* src; short* dst; int ldS, ldD, k0, n0;
  if (id < 72) { int tk = id / 3, tn = id % 3; src = Wq; dst = Wt;  ldS = 192; ldD = 1536; k0 = tk * 64; n0 = tn * 64; }
  else         { id -= 72;                     src = Wo; dst = WtO; ldS = 768; ldD = 64;   k0 = 0;       n0 = id * 64; }
  const int tid = threadIdx.x;
  const int r = tid >> 2, cq = (tid & 3) * 16;
  const float* sp = src + (size_t)(k0 + r) * ldS + n0 + cq;
  float4v v0 = *(const float4v*)(sp);
  float4v v1 = *(const float4v*)(sp + 4);
  float4v v2 = *(const float4v*)(sp + 8);
  float4v v3 = *(const float4v*)(sp + 12);
  short8 s0, s1;
#pragma unroll
  for (int i = 0; i < 4; ++i) {
    s0[i] = (short)f2bf(v0[i]); s0[i + 4] = (short)f2bf(v1[i]);
    s1[i] = (short)f2bf(v2[i]); s1[i + 4] = (short)f2bf(v3[i]);
  }
  *(short8*)(tl + r * 72 + cq) = s0;
  *(short8*)(tl + r * 72 + cq + 8) = s1;
  __syncthreads();
  short8 o0, o1;
#pragma unroll
  for (int j = 0; j < 8; ++j) {
    o0[j] = tl[(cq + j) * 72 + r];
    o1[j] = tl[(cq + 8 + j) * 72 + r];
  }
  short* dp = dst + (size_t)(n0 + r) * ldD + k0 + cq;
  *(short8*)(dp) = o0;
  *(short8*)(dp + 8) = o1;
}

// ---------------------------------------------------------------------------
// k_qkv: qkv = x @ W_qkv + b; writes fragment-native Qf/Kf/Vf.
// 256 blocks x 256 thr (4 waves). Block = 64 rows x 192 cols. Wave = 64r x 48c.
// Fragment layouts (per batch, 32x32x16 MFMA order):
//   Qf/Kf: [t32=row>>5][i=d>>4][h=(d>>3)&1][c=row&31][e=d&7]
//   Vf   : [t32=key>>5][dc=d>>5][s=(key>>4)&1][h=(key>>3)&1][c=d&31][e=key&7]
// ---------------------------------------------------------------------------
__global__ __launch_bounds__(256) void k_qkv(
    const float* __restrict__ x, const short* __restrict__ Wt,
    const float* __restrict__ bq, short* __restrict__ Qf,
    short* __restrict__ Kf, short* __restrict__ Vf) {
  __shared__ __align__(16) short xl[2][64 * 72];
  const int tid = threadIdx.x;
  const int w = tid >> 6, lane = tid & 63, lo = lane & 15, hi = lane >> 4;
  const int m0 = blockIdx.x * 64;
  const int cb = w * 48;
  const float KSC = 0.18033688011112042f;  // (1/8) * log2(e)

  float4v acc[4][3];
#pragma unroll
  for (int r = 0; r < 4; ++r)
#pragma unroll
    for (int c = 0; c < 3; ++c) acc[r][c] = (float4v)0.0f;

  const int xr = tid >> 2, xc = (tid & 3) * 16;
  const float* xrow = x + (size_t)(m0 + xr) * 1536 + xc;
  short* xlw0 = &xl[0][xr * 72 + xc];
  short* xlw1 = &xl[1][xr * 72 + xc];

  float4v xv0 = *(const float4v*)(xrow + 0);
  float4v xv1 = *(const float4v*)(xrow + 4);
  float4v xv2 = *(const float4v*)(xrow + 8);
  float4v xv3 = *(const float4v*)(xrow + 12);
  short8 bcur[3][2];
#pragma unroll
  for (int c = 0; c < 3; ++c)
#pragma unroll
    for (int ks = 0; ks < 2; ++ks)
      bcur[c][ks] = ldg8(Wt + (size_t)(cb + c * 16 + lo) * 1536 + ks * 32 + hi * 8);
  {
    short8 s0, s1;
#pragma unroll
    for (int i = 0; i < 4; ++i) {
      s0[i] = (short)f2bf(xv0[i]); s0[i + 4] = (short)f2bf(xv1[i]);
      s1[i] = (short)f2bf(xv2[i]); s1[i + 4] = (short)f2bf(xv3[i]);
    }
    *(short8*)(xlw0) = s0; *(short8*)(xlw0 + 8) = s1;
  }
  __syncthreads();

  for (int kk = 0; kk < 24; ++kk) {
    const int cur = kk & 1;
    short8 bnxt[3][2];
    if (kk < 23) {
      const int k1 = (kk + 1) * 64;
      xv0 = *(const float4v*)(xrow + k1 + 0);
      xv1 = *(const float4v*)(xrow + k1 + 4);
      xv2 = *(const float4v*)(xrow + k1 + 8);
      xv3 = *(const float4v*)(xrow + k1 + 12);
#pragma unroll
      for (int c = 0; c < 3; ++c)
#pragma unroll
        for (int ks = 0; ks < 2; ++ks)
          bnxt[c][ks] = ldg8(Wt + (size_t)(cb + c * 16 + lo) * 1536 + k1 + ks * 32 + hi * 8);
    }
    const short* xb = &xl[cur][0];
#pragma unroll
    for (int r = 0; r < 4; ++r) {
      short8 a0 = *(const short8*)(xb + (r * 16 + lo) * 72 + hi * 8);
      short8 a1 = *(const short8*)(xb + (r * 16 + lo) * 72 + 32 + hi * 8);
#pragma unroll
      for (int c = 0; c < 3; ++c) {
        acc[r][c] = MFMA16(a0, bcur[c][0], acc[r][c]);
        acc[r][c] = MFMA16(a1, bcur[c][1], acc[r][c]);
      }
    }
    if (kk < 23) {
      short8 s0, s1;
#pragma unroll
      for (int i = 0; i < 4; ++i) {
        s0[i] = (short)f2bf(xv0[i]); s0[i + 4] = (short)f2bf(xv1[i]);
        s1[i] = (short)f2bf(xv2[i]); s1[i + 4] = (short)f2bf(xv3[i]);
      }
      short* dst = cur ? xlw0 : xlw1;
      *(short8*)(dst) = s0; *(short8*)(dst + 8) = s1;
#pragma unroll
      for (int c = 0; c < 3; ++c) { bcur[c][0] = bnxt[c][0]; bcur[c][1] = bnxt[c][1]; }
    }
    __syncthreads();
  }

  float bb[3];
#pragma unroll
  for (int c = 0; c < 3; ++c) bb[c] = bq[cb + c * 16 + lo];

  const int b = m0 >> 11;
  const int row0 = m0 & 2047;  // batch-local row of block start (64-aligned)
  short* vbuf = &xl[0][0];     // [64 keys][72 pad], d = 0..63

#pragma unroll
  for (int r = 0; r < 4; ++r)
#pragma unroll
    for (int c = 0; c < 3; ++c) {
      const int colb = cb + c * 16;
#pragma unroll
      for (int j = 0; j < 4; ++j) {
        const int rl = row0 + r * 16 + hi * 4 + j;  // batch-local row
        float vv = acc[r][c][j] + bb[c];
        if (colb < 64) vv *= KSC;  // q: fold softmax scale (exp2 domain)
        unsigned short u = f2bf(vv);
        if (colb < 128) {
          const int d = (colb < 64) ? (colb + lo) : (colb - 64 + lo);
          short* base = (colb < 64) ? Qf : Kf;
          // [b][t32][i][h][c32][e]
          const size_t idx = ((((size_t)b * 64 + (rl >> 5)) * 4 + (d >> 4)) * 2 +
                              ((d >> 3) & 1)) * 256 + (rl & 31) * 8 + (d & 7);
          base[idx] = (short)u;
        } else {
          vbuf[(r * 16 + hi * 4 + j) * 72 + (colb - 128) + lo] = (short)u;
        }
      }
    }
  __syncthreads();

  // V fragment store from LDS transpose: thread (dr, kq) owns d=dr, 16 keys.
  const int dr = tid >> 2, kq = (tid & 3) * 16;
  short8 o0, o1;
#pragma unroll
  for (int j = 0; j < 8; ++j) {
    o0[j] = vbuf[(kq + j) * 72 + dr];        // keys kq..kq+7   (h=0)
    o1[j] = vbuf[(kq + 8 + j) * 72 + dr];    // keys kq+8..kq+15 (h=1)
  }
  const int kg = (row0 + kq) >> 5, s = (kq >> 4) & 1;
  const int dc = dr >> 5, c32 = dr & 31;
  // [b][kg][dc][s][h][c32][e]
  short* vp = Vf + (((((((size_t)b * 64 + kg) * 2 + dc) * 2 + s) * 2) + 0) * 32 + c32) * 8;
  *(short8*)(vp) = o0;
  *(short8*)(vp + 256) = o1;  // h=1 slot is +32*8
}

// ---------------------------------------------------------------------------
// k_attn: all-builtin split-K flash attn, 32x32x16 tiles, no LDS, all loads
// coalesced (fragment-native operands). Grid = 128*nsplit blocks x 256 thr.
// ---------------------------------------------------------------------------
__global__ __launch_bounds__(256) void k_attn(
    const short* __restrict__ Qf, const short* __restrict__ Kf,
    const short* __restrict__ Vf, short* __restrict__ att,
    float* __restrict__ accP, float* __restrict__ lP,
    int nsplit, int ktps) {
  const int tid = threadIdx.x;
  const int w = tid >> 6, lane = tid & 63;
  const int c = lane & 31, h = lane >> 5;
  const int unit = blockIdx.x & 127;
  const int split = blockIdx.x >> 7;
  const int b = unit >> 4;                    // 16 blocks per batch
  const int q0 = (unit & 15) * 128 + w * 32;
  const size_t g0 = (size_t)b * 2048 + q0;
  const int qg = q0 >> 5;

  // Q (B-operand): [b][qg][i][h][c][e] -> base + lane*8, 1KB coalesced
  short8 qf[4];
#pragma unroll
  for (int i = 0; i < 4; ++i)
    qf[i] = ldg8(Qf + (((size_t)b * 64 + qg) * 4 + i) * 512 + lane * 8);

  float lp = 0.0f;
  float16v acc0 = (float16v)0.0f;   // O^T d 0..31
  float16v acc1 = (float16v)0.0f;   // O^T d 32..63

  const int kg0 = split * ktps * 2;  // 32-key groups per split

  for (int kt = 0; kt < ktps; ++kt) {
#pragma unroll
    for (int s = 0; s < 2; ++s) {
      const int kg = kg0 + kt * 2 + s;
      const short* kbase = Kf + ((size_t)b * 64 + kg) * 2048 + lane * 8;
      short8 kf0 = ldg8(kbase);
      short8 kf1 = ldg8(kbase + 512);
      short8 kf2 = ldg8(kbase + 1024);
      short8 kf3 = ldg8(kbase + 1536);
      float16v sf = (float16v)0.0f;
      sf = MFMA32(kf0, qf[0], sf);
      sf = MFMA32(kf1, qf[1], sf);
      sf = MFMA32(kf2, qf[2], sf);
      sf = MFMA32(kf3, qf[3], sf);
      // p = exp2(sf) (already in exp2 domain); truncate to bf16; l from
      // the truncated values so P/l bias cancels in O/l.
      unsigned wpk[8];
#pragma unroll
      for (int m = 0; m < 8; ++m) {
        float p0 = __builtin_amdgcn_exp2f(sf[2 * m]);
        float p1 = __builtin_amdgcn_exp2f(sf[2 * m + 1]);
        unsigned u0 = __builtin_bit_cast(unsigned, p0) & 0xFFFF0000u;
        unsigned u1 = __builtin_bit_cast(unsigned, p1) & 0xFFFF0000u;
        lp += __builtin_bit_cast(float, u0) + __builtin_bit_cast(float, u1);
        wpk[m] = (u0 >> 16) | u1;
      }
      // Exchange halves: after swaps, wpk[0..3] = B-frag of key-half T0,
      // wpk[4..7] = key-half T1.
      plswap(wpk[0], wpk[2]);
      plswap(wpk[1], wpk[3]);
      plswap(wpk[4], wpk[6]);
      plswap(wpk[5], wpk[7]);
      union { unsigned u[4]; short8 s8; } bt0, bt1;
      bt0.u[0] = wpk[0]; bt0.u[1] = wpk[1]; bt0.u[2] = wpk[2]; bt0.u[3] = wpk[3];
      bt1.u[0] = wpk[4]; bt1.u[1] = wpk[5]; bt1.u[2] = wpk[6]; bt1.u[3] = wpk[7];

      // V^T (A-operand): [b][kg][dc][t][h][c][e] -> base + lane*8
      const short* vbase = Vf + ((size_t)b * 64 + kg) * 2048 + lane * 8;
      short8 vf00 = ldg8(vbase);          // dc=0, keys T0
      short8 vf01 = ldg8(vbase + 512);    // dc=0, keys T1
      short8 vf10 = ldg8(vbase + 1024);   // dc=1, keys T0
      short8 vf11 = ldg8(vbase + 1536);   // dc=1, keys T1
      acc0 = MFMA32(vf00, bt0.s8, acc0);
      acc0 = MFMA32(vf01, bt1.s8, acc0);
      acc1 = MFMA32(vf10, bt0.s8, acc1);
      acc1 = MFMA32(vf11, bt1.s8, acc1);
    }
  }

  // combine per-half partial row sums (lanes c and c+32)
  lp += __shfl_xor(lp, 32, 64);

  if (nsplit == 1) {
    const float inv = 1.0f / lp;
#pragma unroll
    for (int g = 0; g < 4; ++g) {
      short4v r0, r1;
#pragma unroll
      for (int r = 0; r < 4; ++r) {
        r0[r] = (short)f2bf(acc0[4 * g + r] * inv);
        r1[r] = (short)f2bf(acc1[4 * g + r] * inv);
      }
      *(short4v*)(att + (g0 + c) * 64 + 8 * g + 4 * h) = r0;
      *(short4v*)(att + (g0 + c) * 64 + 32 + 8 * g + 4 * h) = r1;
    }
  } else {
    const size_t prow = (size_t)split * 16384 + g0 + c;
#pragma unroll
    for (int g = 0; g < 4; ++g) {
      float4v a0, a1;
#pragma unroll
      for (int r = 0; r < 4; ++r) { a0[r] = acc0[4 * g + r]; a1[r] = acc1[4 * g + r]; }
      *(float4v*)(accP + prow * 64 + 8 * g + 4 * h) = a0;
      *(float4v*)(accP + prow * 64 + 32 + 8 * g + 4 * h) = a1;
    }
    if (h == 0) lP[prow] = lp;
  }
}

// ---------------------------------------------------------------------------
// k_comb: merge split-K partials (plain sums, no max-track). 1024 blks x 256.
// ---------------------------------------------------------------------------
__global__ __launch_bounds__(256) void k_comb(
    const float* __restrict__ accP, const float* __restrict__ lP,
    short* __restrict__ att, int nsplit) {
  const int gid = blockIdx.x * 256 + threadIdx.x;
  const int row = gid >> 4;
  const int dq = (gid & 15) * 4;
  float L = 0.0f;
  float4v o = (float4v)0.0f;
  for (int s = 0; s < nsplit; ++s) {
    const size_t pr = (size_t)s * 16384 + row;
    L += lP[pr];
    const float4v a = *(const float4v*)(accP + pr * 64 + dq);
    o += a;
  }
  const float inv = 1.0f / L;
  short4v r;
#pragma unroll
  for (int j = 0; j < 4; ++j) r[j] = (short)f2bf(o[j] * inv);
  *(short4v*)(att + (size_t)row * 64 + dq) = r;
}

// ---------------------------------------------------------------------------
// k_out: out = att @ W_out + b_out (fp32 out). 256 blocks x 512 thr (8 waves).
// ---------------------------------------------------------------------------
__global__ __launch_bounds__(512) void k_out(
    const short* __restrict__ att, const short* __restrict__ WtO,
    const float* __restrict__ bo, float* __restrict__ out) {
  const int tid = threadIdx.x;
  const int w = tid >> 6, lane = tid & 63, lo = lane & 15, hi = lane >> 4;
  const int wr = w >> 2, wc = (w & 3) * 192;
  const int m0 = blockIdx.x * 64 + wr * 32;

  short8 af[2][2];
#pragma unroll
  for (int rf = 0; rf < 2; ++rf) {
    const short* ap = att + (size_t)(m0 + rf * 16 + lo) * 64 + hi * 8;
    af[rf][0] = ldg8(ap);
    af[rf][1] = ldg8(ap + 32);
  }
  float4v acc[2][12];
#pragma unroll
  for (int rf = 0; rf < 2; ++rf)
#pragma unroll
    for (int c = 0; c < 12; ++c) acc[rf][c] = (float4v)0.0f;

#pragma unroll
  for (int c = 0; c < 12; ++c) {
    const short* bp = WtO + (size_t)(wc + c * 16 + lo) * 64 + hi * 8;
    short8 b0 = ldg8(bp);
    short8 b1 = ldg8(bp + 32);
#pragma unroll
    for (int rf = 0; rf < 2; ++rf) {
      acc[rf][c] = MFMA16(af[rf][0], b0, acc[rf][c]);
      acc[rf][c] = MFMA16(af[rf][1], b1, acc[rf][c]);
    }
  }
#pragma unroll
  for (int c = 0; c < 12; ++c) {
    const float bb = bo[wc + c * 16 + lo];
#pragma unroll
    for (int rf = 0; rf < 2; ++rf)
#pragma unroll
      for (int j = 0; j < 4; ++j)
        out[(size_t)(m0 + rf * 16 + hi * 4 + j) * 768 + wc + c * 16 + lo] =
            acc[rf][c][j] + bb;
  }
}

extern "C" void kernel_launch(void* const* d_in, const int* in_sizes, int n_in,
                              void* d_out, int out_size, void* d_ws, size_t ws_size,
                              hipStream_t stream) {
  (void)in_sizes; (void)n_in; (void)out_size;
  const float* x  = (const float*)d_in[0];
  const float* Wq = (const float*)d_in[1];
  const float* bq = (const float*)d_in[2];
  const float* Wo = (const float*)d_in[3];
  const float* bo = (const float*)d_in[4];
  float* out = (float*)d_out;

  char* ws = (char*)d_ws;
  short* Qf  = (short*)(ws);
  short* Kf  = (short*)(ws + 2097152);
  short* Vf  = (short*)(ws + 4194304);
  short* att = (short*)(ws + 6291456);
  short* Wt  = (short*)(ws + 8388608);
  short* WtO = (short*)(ws + 8978432);

  const size_t pbase = 9076736;
  int nsplit = 1;
  if (ws_size >= pbase + 8u * (4194304u + 65536u)) nsplit = 8;
  else if (ws_size >= pbase + 4u * (4194304u + 65536u)) nsplit = 4;
  float* accP = (float*)(ws + pbase);
  float* lP   = (float*)(ws + pbase + (size_t)nsplit * 4194304u);
  const int ktps = 32 / nsplit;

  k_prep<<<84, 256, 0, stream>>>(Wq, Wo, Wt, WtO);
  k_qkv<<<256, 256, 0, stream>>>(x, Wt, bq, Qf, Kf, Vf);
  k_attn<<<128 * nsplit, 256, 0, stream>>>(Qf, Kf, Vf, att, accP, lP, nsplit, ktps);
  if (nsplit > 1)
    k_comb<<<1024, 256, 0, stream>>>(accP, lP, att, nsplit);
  k_out<<<256, 512, 0, stream>>>(att, WtO, bo, out);
}

// Round 7
// 82.178 us; speedup vs baseline: 1.6513x; 1.1458x over previous
//
#include <hip/hip_runtime.h>
#include <hip/hip_bf16.h>

// TinyAttention fused pipeline, bf16 MFMA path.
// Round 7: bf16 split-K partials (half the partial traffic), 2-stage
// software-pipelined k_attn subtile loop (named regs, no dyn indexing),
// k_qkv epilogue stages Q/K through LDS for coalesced 16B fragment stores.
// ws layout (bytes):
//   Qf  bf16 [8][64][4][2][32][8]    @ 0         (2,097,152)  (q pre-scaled)
//   Kf  bf16 [8][64][4][2][32][8]    @ 2,097,152 (2,097,152)
//   Vf  bf16 [8][64][2][2][2][32][8] @ 4,194,304 (2,097,152)
//   att bf16 [16384][64]             @ 6,291,456 (2,097,152)
//   Wt  bf16 [192][1536]             @ 8,388,608 (589,824)
//   WtO bf16 [768][64]               @ 8,978,432 (98,304)
//   accPb bf16 [S][16384][64]        @ 9,076,736 (S*2,097,152)
//   lP    f32  [S][16384]            @ after accPb (S*65,536)

typedef __attribute__((ext_vector_type(8))) short short8;
typedef __attribute__((ext_vector_type(4))) short short4v;
typedef __attribute__((ext_vector_type(4))) float float4v;
typedef __attribute__((ext_vector_type(16))) float float16v;

#define MFMA16(a, b, c) __builtin_amdgcn_mfma_f32_16x16x32_bf16((a), (b), (c), 0, 0, 0)
#define MFMA32(a, b, c) __builtin_amdgcn_mfma_f32_32x32x16_bf16((a), (b), (c), 0, 0, 0)

// v_permlane32_swap_b32 a, b:  a[32+i] <-> b[i]  (VALU cross-lane, no DS)
static __device__ __forceinline__ void plswap(unsigned& a, unsigned& b) {
  asm("v_permlane32_swap_b32 %0, %1" : "+v"(a), "+v"(b));
}

static __device__ __forceinline__ unsigned short f2bf(float x) {
  union { float f; unsigned u; } v; v.f = x;
  return (unsigned short)((v.u + 0x7FFFu + ((v.u >> 16) & 1u)) >> 16);
}
static __device__ __forceinline__ float bf2f(short x) {
  union { unsigned u; float f; } v;
  v.u = ((unsigned)(unsigned short)x) << 16;
  return v.f;
}
static __device__ __forceinline__ short8 ldg8(const short* p) {
  return *(const short8*)p;
}

// ---------------------------------------------------------------------------
// k_prep: W_qkv [1536][192] f32 -> Wt [192][1536] bf16 (blocks 0..71)
//         W_out [64][768]  f32 -> WtO [768][64]  bf16 (blocks 72..83)
// ---------------------------------------------------------------------------
__global__ __launch_bounds__(256) void k_prep(
    const float* __restrict__ Wq, const float* __restrict__ Wo,
    short* __restrict__ Wt, short* __restrict__ WtO) {
  __shared__ __align__(16) short tl[64 * 72];
  int id = blockIdx.x;
  const float* src; short* dst; int ldS, ldD, k0, n0;
  if (id < 72) { int tk = id / 3, tn = id % 3; src = Wq; dst = Wt;  ldS = 192; ldD = 1536; k0 = tk * 64; n0 = tn * 64; }
  else         { id -= 72;                     src = Wo; dst = WtO; ldS = 768; ldD = 64;   k0 = 0;       n0 = id * 64; }
  const int tid = threadIdx.x;
  const int r = tid >> 2, cq = (tid & 3) * 16;
  const float* sp = src + (size_t)(k0 + r) * ldS + n0 + cq;
  float4v v0 = *(const float4v*)(sp);
  float4v v1 = *(const float4v*)(sp + 4);
  float4v v2 = *(const float4v*)(sp + 8);
  float4v v3 = *(const float4v*)(sp + 12);
  short8 s0, s1;
#pragma unroll
  for (int i = 0; i < 4; ++i) {
    s0[i] = (short)f2bf(v0[i]); s0[i + 4] = (short)f2bf(v1[i]);
    s1[i] = (short)f2bf(v2[i]); s1[i + 4] = (short)f2bf(v3[i]);
  }
  *(short8*)(tl + r * 72 + cq) = s0;
  *(short8*)(tl + r * 72 + cq + 8) = s1;
  __syncthreads();
  short8 o0, o1;
#pragma unroll
  for (int j = 0; j < 8; ++j) {
    o0[j] = tl[(cq + j) * 72 + r];
    o1[j] = tl[(cq + 8 + j) * 72 + r];
  }
  short* dp = dst + (size_t)(n0 + r) * ldD + k0 + cq;
  *(short8*)(dp) = o0;
  *(short8*)(dp + 8) = o1;
}

// ---------------------------------------------------------------------------
// k_qkv: qkv = x @ W_qkv + b; writes fragment-native Qf/Kf/Vf (all coalesced).
// 256 blocks x 256 thr (4 waves). Block = 64 rows x 192 cols. Wave = 64r x 48c.
// Epilogue: q,k,v all staged in LDS, then 16B fragment-order stores.
// ---------------------------------------------------------------------------
__global__ __launch_bounds__(256) void k_qkv(
    const float* __restrict__ x, const short* __restrict__ Wt,
    const float* __restrict__ bq, short* __restrict__ Qf,
    short* __restrict__ Kf, short* __restrict__ Vf) {
  __shared__ __align__(16) short xl[3][64 * 72];
  const int tid = threadIdx.x;
  const int w = tid >> 6, lane = tid & 63, lo = lane & 15, hi = lane >> 4;
  const int m0 = blockIdx.x * 64;
  const int cb = w * 48;
  const float KSC = 0.18033688011112042f;  // (1/8) * log2(e)

  float4v acc[4][3];
#pragma unroll
  for (int r = 0; r < 4; ++r)
#pragma unroll
    for (int c = 0; c < 3; ++c) acc[r][c] = (float4v)0.0f;

  const int xr = tid >> 2, xc = (tid & 3) * 16;
  const float* xrow = x + (size_t)(m0 + xr) * 1536 + xc;
  short* xlw0 = &xl[0][xr * 72 + xc];
  short* xlw1 = &xl[1][xr * 72 + xc];

  float4v xv0 = *(const float4v*)(xrow + 0);
  float4v xv1 = *(const float4v*)(xrow + 4);
  float4v xv2 = *(const float4v*)(xrow + 8);
  float4v xv3 = *(const float4v*)(xrow + 12);
  short8 bcur[3][2];
#pragma unroll
  for (int c = 0; c < 3; ++c)
#pragma unroll
    for (int ks = 0; ks < 2; ++ks)
      bcur[c][ks] = ldg8(Wt + (size_t)(cb + c * 16 + lo) * 1536 + ks * 32 + hi * 8);
  {
    short8 s0, s1;
#pragma unroll
    for (int i = 0; i < 4; ++i) {
      s0[i] = (short)f2bf(xv0[i]); s0[i + 4] = (short)f2bf(xv1[i]);
      s1[i] = (short)f2bf(xv2[i]); s1[i + 4] = (short)f2bf(xv3[i]);
    }
    *(short8*)(xlw0) = s0; *(short8*)(xlw0 + 8) = s1;
  }
  __syncthreads();

  for (int kk = 0; kk < 24; ++kk) {
    const int cur = kk & 1;
    short8 bnxt[3][2];
    if (kk < 23) {
      const int k1 = (kk + 1) * 64;
      xv0 = *(const float4v*)(xrow + k1 + 0);
      xv1 = *(const float4v*)(xrow + k1 + 4);
      xv2 = *(const float4v*)(xrow + k1 + 8);
      xv3 = *(const float4v*)(xrow + k1 + 12);
#pragma unroll
      for (int c = 0; c < 3; ++c)
#pragma unroll
        for (int ks = 0; ks < 2; ++ks)
          bnxt[c][ks] = ldg8(Wt + (size_t)(cb + c * 16 + lo) * 1536 + k1 + ks * 32 + hi * 8);
    }
    const short* xb = &xl[cur][0];
#pragma unroll
    for (int r = 0; r < 4; ++r) {
      short8 a0 = *(const short8*)(xb + (r * 16 + lo) * 72 + hi * 8);
      short8 a1 = *(const short8*)(xb + (r * 16 + lo) * 72 + 32 + hi * 8);
#pragma unroll
      for (int c = 0; c < 3; ++c) {
        acc[r][c] = MFMA16(a0, bcur[c][0], acc[r][c]);
        acc[r][c] = MFMA16(a1, bcur[c][1], acc[r][c]);
      }
    }
    if (kk < 23) {
      short8 s0, s1;
#pragma unroll
      for (int i = 0; i < 4; ++i) {
        s0[i] = (short)f2bf(xv0[i]); s0[i + 4] = (short)f2bf(xv1[i]);
        s1[i] = (short)f2bf(xv2[i]); s1[i + 4] = (short)f2bf(xv3[i]);
      }
      short* dst = cur ? xlw0 : xlw1;
      *(short8*)(dst) = s0; *(short8*)(dst + 8) = s1;
#pragma unroll
      for (int c = 0; c < 3; ++c) { bcur[c][0] = bnxt[c][0]; bcur[c][1] = bnxt[c][1]; }
    }
    __syncthreads();
  }

  float bb[3];
#pragma unroll
  for (int c = 0; c < 3; ++c) bb[c] = bq[cb + c * 16 + lo];

  const int b = m0 >> 11;
  const int row0 = m0 & 2047;  // batch-local 64-aligned row of block start
  short* qbuf = &xl[0][0];     // [64 rows][72 pad], d 0..63
  short* kbuf = &xl[1][0];
  short* vbuf = &xl[2][0];     // [64 keys][72 pad], d 0..63

#pragma unroll
  for (int r = 0; r < 4; ++r)
#pragma unroll
    for (int c = 0; c < 3; ++c) {
      const int colb = cb + c * 16;
      short* buf = (colb < 64) ? qbuf : ((colb < 128) ? kbuf : vbuf);
      const int d0 = (colb & 63) + lo;
#pragma unroll
      for (int j = 0; j < 4; ++j) {
        float vv = acc[r][c][j] + bb[c];
        if (colb < 64) vv *= KSC;  // q: fold softmax scale (exp2 domain)
        buf[(r * 16 + hi * 4 + j) * 72 + d0] = (short)f2bf(vv);
      }
    }
  __syncthreads();

  // Q/K fragment stores: thread = (row rr, 16-d group dq)
  {
    const int rr = tid >> 2, dq = (tid & 3) * 16;
    const int t32 = (row0 + rr) >> 5, c32 = rr & 31, i = dq >> 4;
    short8 q0 = *(const short8*)(qbuf + rr * 72 + dq);
    short8 q1 = *(const short8*)(qbuf + rr * 72 + dq + 8);
    short* qp = Qf + (((size_t)b * 64 + t32) * 4 + i) * 512 + c32 * 8;
    *(short8*)(qp) = q0;
    *(short8*)(qp + 256) = q1;
    short8 k0 = *(const short8*)(kbuf + rr * 72 + dq);
    short8 k1 = *(const short8*)(kbuf + rr * 72 + dq + 8);
    short* kp = Kf + (((size_t)b * 64 + t32) * 4 + i) * 512 + c32 * 8;
    *(short8*)(kp) = k0;
    *(short8*)(kp + 256) = k1;
  }

  // V fragment store: thread (d=dr, keys kq..kq+15), LDS transpose read
  {
    const int dr = tid >> 2, kq = (tid & 3) * 16;
    short8 o0, o1;
#pragma unroll
    for (int j = 0; j < 8; ++j) {
      o0[j] = vbuf[(kq + j) * 72 + dr];        // keys kq..kq+7    (h=0)
      o1[j] = vbuf[(kq + 8 + j) * 72 + dr];    // keys kq+8..kq+15 (h=1)
    }
    const int kg = (row0 + kq) >> 5, s = (kq >> 4) & 1;
    const int dc = dr >> 5, c32 = dr & 31;
    short* vp = Vf + ((((((size_t)b * 64 + kg) * 2 + dc) * 2 + s) * 2) * 32 + c32) * 8;
    *(short8*)(vp) = o0;
    *(short8*)(vp + 256) = o1;  // h=1 slot
  }
}

// ---------------------------------------------------------------------------
// k_attn: split-K flash attn, 32x32x16 tiles, no LDS, coalesced loads,
// 2-stage software-pipelined subtile loop. Grid = 128*nsplit blocks x 256 thr.
// Partials stored bf16 (error ~3e-4 in final output).
// ---------------------------------------------------------------------------
__global__ __launch_bounds__(256) void k_attn(
    const short* __restrict__ Qf, const short* __restrict__ Kf,
    const short* __restrict__ Vf, short* __restrict__ att,
    short* __restrict__ accPb, float* __restrict__ lP,
    int nsplit, int ktps) {
  const int tid = threadIdx.x;
  const int w = tid >> 6, lane = tid & 63;
  const int c = lane & 31, h = lane >> 5;
  const int unit = blockIdx.x & 127;
  const int split = blockIdx.x >> 7;
  const int b = unit >> 4;                    // 16 blocks per batch
  const int q0 = (unit & 15) * 128 + w * 32;
  const size_t g0 = (size_t)b * 2048 + q0;
  const int qg = q0 >> 5;

  short8 qf0 = ldg8(Qf + (((size_t)b * 64 + qg) * 4 + 0) * 512 + lane * 8);
  short8 qf1 = ldg8(Qf + (((size_t)b * 64 + qg) * 4 + 1) * 512 + lane * 8);
  short8 qf2 = ldg8(Qf + (((size_t)b * 64 + qg) * 4 + 2) * 512 + lane * 8);
  short8 qf3 = ldg8(Qf + (((size_t)b * 64 + qg) * 4 + 3) * 512 + lane * 8);

  float lp = 0.0f;
  float16v acc0 = (float16v)0.0f;   // O^T d 0..31
  float16v acc1 = (float16v)0.0f;   // O^T d 32..63

  const int nt = ktps * 2;          // 32-key subtiles in this split
  int kg = split * ktps * 2;
  const short* kb = Kf + ((size_t)b * 64) * 2048 + lane * 8;
  const short* vb = Vf + ((size_t)b * 64) * 2048 + lane * 8;

#define ATTN_STEP(K0, K1, K2, K3, V0, V1, V2, V3)                              \
  do {                                                                         \
    float16v sf = (float16v)0.0f;                                              \
    sf = MFMA32(K0, qf0, sf);                                                  \
    sf = MFMA32(K1, qf1, sf);                                                  \
    sf = MFMA32(K2, qf2, sf);                                                  \
    sf = MFMA32(K3, qf3, sf);                                                  \
    unsigned wpk[8];                                                           \
    _Pragma("unroll")                                                          \
    for (int m = 0; m < 8; ++m) {                                              \
      float p0 = __builtin_amdgcn_exp2f(sf[2 * m]);                            \
      float p1 = __builtin_amdgcn_exp2f(sf[2 * m + 1]);                        \
      unsigned u0 = __builtin_bit_cast(unsigned, p0) & 0xFFFF0000u;            \
      unsigned u1 = __builtin_bit_cast(unsigned, p1) & 0xFFFF0000u;            \
      lp += __builtin_bit_cast(float, u0) + __builtin_bit_cast(float, u1);     \
      wpk[m] = (u0 >> 16) | u1;                                                \
    }                                                                          \
    plswap(wpk[0], wpk[2]);                                                    \
    plswap(wpk[1], wpk[3]);                                                    \
    plswap(wpk[4], wpk[6]);                                                    \
    plswap(wpk[5], wpk[7]);                                                    \
    union { unsigned u[4]; short8 s8; } bt0, bt1;                              \
    bt0.u[0] = wpk[0]; bt0.u[1] = wpk[1]; bt0.u[2] = wpk[2]; bt0.u[3] = wpk[3];\
    bt1.u[0] = wpk[4]; bt1.u[1] = wpk[5]; bt1.u[2] = wpk[6]; bt1.u[3] = wpk[7];\
    acc0 = MFMA32(V0, bt0.s8, acc0);                                           \
    acc0 = MFMA32(V1, bt1.s8, acc0);                                           \
    acc1 = MFMA32(V2, bt0.s8, acc1);                                           \
    acc1 = MFMA32(V3, bt1.s8, acc1);                                           \
  } while (0)

  // prologue: load set A (subtile kg)
  const short* kpA = kb + (size_t)kg * 2048;
  const short* vpA = vb + (size_t)kg * 2048;
  short8 ka0 = ldg8(kpA), ka1 = ldg8(kpA + 512), ka2 = ldg8(kpA + 1024), ka3 = ldg8(kpA + 1536);
  short8 va0 = ldg8(vpA), va1 = ldg8(vpA + 512), va2 = ldg8(vpA + 1024), va3 = ldg8(vpA + 1536);

  for (int t = 0; t < nt; t += 2) {
    // load set B (subtile kg+1) ahead of compute A
    const short* kpB = kb + (size_t)(kg + 1) * 2048;
    const short* vpB = vb + (size_t)(kg + 1) * 2048;
    short8 kb0 = ldg8(kpB), kb1 = ldg8(kpB + 512), kb2 = ldg8(kpB + 1024), kb3 = ldg8(kpB + 1536);
    short8 vb0 = ldg8(vpB), vb1 = ldg8(vpB + 512), vb2 = ldg8(vpB + 1024), vb3 = ldg8(vpB + 1536);

    ATTN_STEP(ka0, ka1, ka2, ka3, va0, va1, va2, va3);

    if (t + 2 < nt) {  // load next set A (subtile kg+2) ahead of compute B
      const short* kpN = kb + (size_t)(kg + 2) * 2048;
      const short* vpN = vb + (size_t)(kg + 2) * 2048;
      ka0 = ldg8(kpN); ka1 = ldg8(kpN + 512); ka2 = ldg8(kpN + 1024); ka3 = ldg8(kpN + 1536);
      va0 = ldg8(vpN); va1 = ldg8(vpN + 512); va2 = ldg8(vpN + 1024); va3 = ldg8(vpN + 1536);
    }

    ATTN_STEP(kb0, kb1, kb2, kb3, vb0, vb1, vb2, vb3);
    kg += 2;
  }
#undef ATTN_STEP

  // combine per-half partial row sums (lanes c and c+32)
  lp += __shfl_xor(lp, 32, 64);

  if (nsplit == 1) {
    const float inv = 1.0f / lp;
#pragma unroll
    for (int g = 0; g < 4; ++g) {
      short4v r0, r1;
#pragma unroll
      for (int r = 0; r < 4; ++r) {
        r0[r] = (short)f2bf(acc0[4 * g + r] * inv);
        r1[r] = (short)f2bf(acc1[4 * g + r] * inv);
      }
      *(short4v*)(att + (g0 + c) * 64 + 8 * g + 4 * h) = r0;
      *(short4v*)(att + (g0 + c) * 64 + 32 + 8 * g + 4 * h) = r1;
    }
  } else {
    const size_t prow = (size_t)split * 16384 + g0 + c;
    short* ap = accPb + prow * 64;
#pragma unroll
    for (int g = 0; g < 4; ++g) {
      short4v a0, a1;
#pragma unroll
      for (int r = 0; r < 4; ++r) {
        a0[r] = (short)f2bf(acc0[4 * g + r]);
        a1[r] = (short)f2bf(acc1[4 * g + r]);
      }
      *(short4v*)(ap + 8 * g + 4 * h) = a0;
      *(short4v*)(ap + 32 + 8 * g + 4 * h) = a1;
    }
    if (h == 0) lP[prow] = lp;
  }
}

// ---------------------------------------------------------------------------
// k_comb: merge bf16 split-K partials (plain sums). 1024 blks x 256.
// ---------------------------------------------------------------------------
__global__ __launch_bounds__(256) void k_comb(
    const short* __restrict__ accPb, const float* __restrict__ lP,
    short* __restrict__ att, int nsplit) {
  const int gid = blockIdx.x * 256 + threadIdx.x;
  const int row = gid >> 4;
  const int dq = (gid & 15) * 4;
  float L = 0.0f;
  float o0 = 0.0f, o1 = 0.0f, o2 = 0.0f, o3 = 0.0f;
  for (int s = 0; s < nsplit; ++s) {
    const size_t pr = (size_t)s * 16384 + row;
    L += lP[pr];
    const short4v a = *(const short4v*)(accPb + pr * 64 + dq);
    o0 += bf2f(a[0]); o1 += bf2f(a[1]); o2 += bf2f(a[2]); o3 += bf2f(a[3]);
  }
  const float inv = 1.0f / L;
  short4v r;
  r[0] = (short)f2bf(o0 * inv);
  r[1] = (short)f2bf(o1 * inv);
  r[2] = (short)f2bf(o2 * inv);
  r[3] = (short)f2bf(o3 * inv);
  *(short4v*)(att + (size_t)row * 64 + dq) = r;
}

// ---------------------------------------------------------------------------
// k_out: out = att @ W_out + b_out (fp32 out). 256 blocks x 512 thr (8 waves).
// ---------------------------------------------------------------------------
__global__ __launch_bounds__(512) void k_out(
    const short* __restrict__ att, const short* __restrict__ WtO,
    const float* __restrict__ bo, float* __restrict__ out) {
  const int tid = threadIdx.x;
  const int w = tid >> 6, lane = tid & 63, lo = lane & 15, hi = lane >> 4;
  const int wr = w >> 2, wc = (w & 3) * 192;
  const int m0 = blockIdx.x * 64 + wr * 32;

  short8 af[2][2];
#pragma unroll
  for (int rf = 0; rf < 2; ++rf) {
    const short* ap = att + (size_t)(m0 + rf * 16 + lo) * 64 + hi * 8;
    af[rf][0] = ldg8(ap);
    af[rf][1] = ldg8(ap + 32);
  }
  float4v acc[2][12];
#pragma unroll
  for (int rf = 0; rf < 2; ++rf)
#pragma unroll
    for (int c = 0; c < 12; ++c) acc[rf][c] = (float4v)0.0f;

#pragma unroll
  for (int c = 0; c < 12; ++c) {
    const short* bp = WtO + (size_t)(wc + c * 16 + lo) * 64 + hi * 8;
    short8 b0 = ldg8(bp);
    short8 b1 = ldg8(bp + 32);
#pragma unroll
    for (int rf = 0; rf < 2; ++rf) {
      acc[rf][c] = MFMA16(af[rf][0], b0, acc[rf][c]);
      acc[rf][c] = MFMA16(af[rf][1], b1, acc[rf][c]);
    }
  }
#pragma unroll
  for (int c = 0; c < 12; ++c) {
    const float bb = bo[wc + c * 16 + lo];
#pragma unroll
    for (int rf = 0; rf < 2; ++rf)
#pragma unroll
      for (int j = 0; j < 4; ++j)
        out[(size_t)(m0 + rf * 16 + hi * 4 + j) * 768 + wc + c * 16 + lo] =
            acc[rf][c][j] + bb;
  }
}

extern "C" void kernel_launch(void* const* d_in, const int* in_sizes, int n_in,
                              void* d_out, int out_size, void* d_ws, size_t ws_size,
                              hipStream_t stream) {
  (void)in_sizes; (void)n_in; (void)out_size;
  const float* x  = (const float*)d_in[0];
  const float* Wq = (const float*)d_in[1];
  const float* bq = (const float*)d_in[2];
  const float* Wo = (const float*)d_in[3];
  const float* bo = (const float*)d_in[4];
  float* out = (float*)d_out;

  char* ws = (char*)d_ws;
  short* Qf  = (short*)(ws);
  short* Kf  = (short*)(ws + 2097152);
  short* Vf  = (short*)(ws + 4194304);
  short* att = (short*)(ws + 6291456);
  short* Wt  = (short*)(ws + 8388608);
  short* WtO = (short*)(ws + 8978432);

  const size_t pbase = 9076736;
  int nsplit = 1;
  if (ws_size >= pbase + 8u * (2097152u + 65536u)) nsplit = 8;
  else if (ws_size >= pbase + 4u * (2097152u + 65536u)) nsplit = 4;
  short* accPb = (short*)(ws + pbase);
  float* lP    = (float*)(ws + pbase + (size_t)nsplit * 2097152u);
  const int ktps = 32 / nsplit;

  k_prep<<<84, 256, 0, stream>>>(Wq, Wo, Wt, WtO);
  k_qkv<<<256, 256, 0, stream>>>(x, Wt, bq, Qf, Kf, Vf);
  k_attn<<<128 * nsplit, 256, 0, stream>>>(Qf, Kf, Vf, att, accPb, lP, nsplit, ktps);
  if (nsplit > 1)
    k_comb<<<1024, 256, 0, stream>>>(accPb, lP, att, nsplit);
  k_out<<<256, 512, 0, stream>>>(att, WtO, bo, out);
}

// Round 8
// 78.333 us; speedup vs baseline: 1.7323x; 1.0491x over previous
//
#include <hip/hip_runtime.h>
#include <hip/hip_bf16.h>

// TinyAttention fused pipeline, bf16 MFMA path.
// Round 8: occupancy-driven regrid (k_qkv 512x256, k_out 512x256) and
// in-block split-K attention (8 waves = 8 key-splits, LDS f32 combine,
// no global partials, no k_comb kernel).
// ws layout (bytes):
//   Qf  bf16 [8][64][4][2][32][8]    @ 0         (2,097,152)  (q pre-scaled)
//   Kf  bf16 [8][64][4][2][32][8]    @ 2,097,152 (2,097,152)
//   Vf  bf16 [8][64][2][2][2][32][8] @ 4,194,304 (2,097,152)
//   att bf16 [16384][64]             @ 6,291,456 (2,097,152)
//   Wt  bf16 [192][1536]             @ 8,388,608 (589,824)
//   WtO bf16 [768][64]               @ 8,978,432 (98,304)

typedef __attribute__((ext_vector_type(8))) short short8;
typedef __attribute__((ext_vector_type(4))) short short4v;
typedef __attribute__((ext_vector_type(4))) float float4v;
typedef __attribute__((ext_vector_type(16))) float float16v;

#define MFMA16(a, b, c) __builtin_amdgcn_mfma_f32_16x16x32_bf16((a), (b), (c), 0, 0, 0)
#define MFMA32(a, b, c) __builtin_amdgcn_mfma_f32_32x32x16_bf16((a), (b), (c), 0, 0, 0)

// v_permlane32_swap_b32 a, b:  a[32+i] <-> b[i]  (VALU cross-lane, no DS)
static __device__ __forceinline__ void plswap(unsigned& a, unsigned& b) {
  asm("v_permlane32_swap_b32 %0, %1" : "+v"(a), "+v"(b));
}

static __device__ __forceinline__ unsigned short f2bf(float x) {
  union { float f; unsigned u; } v; v.f = x;
  return (unsigned short)((v.u + 0x7FFFu + ((v.u >> 16) & 1u)) >> 16);
}
static __device__ __forceinline__ short8 ldg8(const short* p) {
  return *(const short8*)p;
}

// ---------------------------------------------------------------------------
// k_prep: W_qkv [1536][192] f32 -> Wt [192][1536] bf16 (blocks 0..71)
//         W_out [64][768]  f32 -> WtO [768][64]  bf16 (blocks 72..83)
// ---------------------------------------------------------------------------
__global__ __launch_bounds__(256) void k_prep(
    const float* __restrict__ Wq, const float* __restrict__ Wo,
    short* __restrict__ Wt, short* __restrict__ WtO) {
  __shared__ __align__(16) short tl[64 * 72];
  int id = blockIdx.x;
  const float* src; short* dst; int ldS, ldD, k0, n0;
  if (id < 72) { int tk = id / 3, tn = id % 3; src = Wq; dst = Wt;  ldS = 192; ldD = 1536; k0 = tk * 64; n0 = tn * 64; }
  else         { id -= 72;                     src = Wo; dst = WtO; ldS = 768; ldD = 64;   k0 = 0;       n0 = id * 64; }
  const int tid = threadIdx.x;
  const int r = tid >> 2, cq = (tid & 3) * 16;
  const float* sp = src + (size_t)(k0 + r) * ldS + n0 + cq;
  float4v v0 = *(const float4v*)(sp);
  float4v v1 = *(const float4v*)(sp + 4);
  float4v v2 = *(const float4v*)(sp + 8);
  float4v v3 = *(const float4v*)(sp + 12);
  short8 s0, s1;
#pragma unroll
  for (int i = 0; i < 4; ++i) {
    s0[i] = (short)f2bf(v0[i]); s0[i + 4] = (short)f2bf(v1[i]);
    s1[i] = (short)f2bf(v2[i]); s1[i + 4] = (short)f2bf(v3[i]);
  }
  *(short8*)(tl + r * 72 + cq) = s0;
  *(short8*)(tl + r * 72 + cq + 8) = s1;
  __syncthreads();
  short8 o0, o1;
#pragma unroll
  for (int j = 0; j < 8; ++j) {
    o0[j] = tl[(cq + j) * 72 + r];
    o1[j] = tl[(cq + 8 + j) * 72 + r];
  }
  short* dp = dst + (size_t)(n0 + r) * ldD + k0 + cq;
  *(short8*)(dp) = o0;
  *(short8*)(dp + 8) = o1;
}

// ---------------------------------------------------------------------------
// k_qkv: qkv = x @ W_qkv + b; writes fragment-native Qf/Kf/Vf (coalesced).
// 512 blocks x 256 thr (4 waves): block = 32 rows x 192 cols, wave = 32r x 48c.
// 2 blocks/CU -> 2 waves/SIMD of latency hiding (was 1 at 64-row tiles).
// ---------------------------------------------------------------------------
__global__ __launch_bounds__(256) void k_qkv(
    const float* __restrict__ x, const short* __restrict__ Wt,
    const float* __restrict__ bq, short* __restrict__ Qf,
    short* __restrict__ Kf, short* __restrict__ Vf) {
  __shared__ __align__(16) short xl[2][32 * 72];
  __shared__ __align__(16) short qbuf[32 * 72], kstg[32 * 72], vstg[32 * 72];
  const int tid = threadIdx.x;
  const int w = tid >> 6, lane = tid & 63, lo = lane & 15, hi = lane >> 4;
  const int m0 = blockIdx.x * 32;
  const int cb = w * 48;
  const float KSC = 0.18033688011112042f;  // (1/8) * log2(e)

  float4v acc[2][3];
#pragma unroll
  for (int r = 0; r < 2; ++r)
#pragma unroll
    for (int c = 0; c < 3; ++c) acc[r][c] = (float4v)0.0f;

  const int xr = tid >> 3, xc = (tid & 7) * 8;
  const float* xrow = x + (size_t)(m0 + xr) * 1536 + xc;
  short* xlw0 = &xl[0][xr * 72 + xc];
  short* xlw1 = &xl[1][xr * 72 + xc];

  float4v xv0 = *(const float4v*)(xrow + 0);
  float4v xv1 = *(const float4v*)(xrow + 4);
  short8 bcur[3][2];
#pragma unroll
  for (int c = 0; c < 3; ++c)
#pragma unroll
    for (int ks = 0; ks < 2; ++ks)
      bcur[c][ks] = ldg8(Wt + (size_t)(cb + c * 16 + lo) * 1536 + ks * 32 + hi * 8);
  {
    short8 s0;
#pragma unroll
    for (int i = 0; i < 4; ++i) { s0[i] = (short)f2bf(xv0[i]); s0[i + 4] = (short)f2bf(xv1[i]); }
    *(short8*)(xlw0) = s0;
  }
  __syncthreads();

  for (int kk = 0; kk < 24; ++kk) {
    const int cur = kk & 1;
    short8 bnxt[3][2];
    if (kk < 23) {
      const int k1 = (kk + 1) * 64;
      xv0 = *(const float4v*)(xrow + k1 + 0);
      xv1 = *(const float4v*)(xrow + k1 + 4);
#pragma unroll
      for (int c = 0; c < 3; ++c)
#pragma unroll
        for (int ks = 0; ks < 2; ++ks)
          bnxt[c][ks] = ldg8(Wt + (size_t)(cb + c * 16 + lo) * 1536 + k1 + ks * 32 + hi * 8);
    }
    const short* xb = &xl[cur][0];
#pragma unroll
    for (int r = 0; r < 2; ++r) {
      short8 a0 = *(const short8*)(xb + (r * 16 + lo) * 72 + hi * 8);
      short8 a1 = *(const short8*)(xb + (r * 16 + lo) * 72 + 32 + hi * 8);
#pragma unroll
      for (int c = 0; c < 3; ++c) {
        acc[r][c] = MFMA16(a0, bcur[c][0], acc[r][c]);
        acc[r][c] = MFMA16(a1, bcur[c][1], acc[r][c]);
      }
    }
    if (kk < 23) {
      short8 s0;
#pragma unroll
      for (int i = 0; i < 4; ++i) { s0[i] = (short)f2bf(xv0[i]); s0[i + 4] = (short)f2bf(xv1[i]); }
      *(short8*)(cur ? xlw0 : xlw1) = s0;
#pragma unroll
      for (int c = 0; c < 3; ++c) { bcur[c][0] = bnxt[c][0]; bcur[c][1] = bnxt[c][1]; }
    }
    __syncthreads();
  }

  float bb[3];
#pragma unroll
  for (int c = 0; c < 3; ++c) bb[c] = bq[cb + c * 16 + lo];

  const int b = m0 >> 11;
  const int row0 = m0 & 2047;  // batch-local 32-aligned row of block start

#pragma unroll
  for (int r = 0; r < 2; ++r)
#pragma unroll
    for (int c = 0; c < 3; ++c) {
      const int colb = cb + c * 16;
      short* buf = (colb < 64) ? qbuf : ((colb < 128) ? kstg : vstg);
      const int d0 = (colb & 63) + lo;
#pragma unroll
      for (int j = 0; j < 4; ++j) {
        float vv = acc[r][c][j] + bb[c];
        if (colb < 64) vv *= KSC;  // q: fold softmax scale (exp2 domain)
        buf[(r * 16 + hi * 4 + j) * 72 + d0] = (short)f2bf(vv);
      }
    }
  __syncthreads();

  // Q/K fragment stores: thread = (row rr 0..31, 8-d group dq)
  {
    const int rr = tid >> 3, dq = (tid & 7) * 8;
    const int t32 = row0 >> 5, i = dq >> 4, h = (dq >> 3) & 1;
    const size_t base = ((((size_t)b * 64 + t32) * 4 + i) * 2 + h) * 256 + rr * 8;
    *(short8*)(Qf + base) = *(const short8*)(qbuf + rr * 72 + dq);
    *(short8*)(Kf + base) = *(const short8*)(kstg + rr * 72 + dq);
  }

  // V fragment store: thread = (d=dr 0..63, 8-key group kq8), LDS transpose
  {
    const int dr = tid >> 2, kq8 = (tid & 3) * 8;
    short8 o0;
#pragma unroll
    for (int j = 0; j < 8; ++j) o0[j] = vstg[(kq8 + j) * 72 + dr];
    const int kg = row0 >> 5, s = (kq8 >> 4) & 1, h = (kq8 >> 3) & 1;
    const int dc = dr >> 5, c32 = dr & 31;
    short* vp = Vf + ((((((size_t)b * 64 + kg) * 2 + dc) * 2 + s) * 2 + h) * 32 + c32) * 8;
    *(short8*)(vp) = o0;
  }
}

// ---------------------------------------------------------------------------
// k_attn: in-block split-K flash attn. 512 blocks x 512 thr (8 waves).
// Wave w handles keys [256w, 256w+256) for the block's 32 q-rows with the
// 2-stage pipelined 32x32x16 loop; partials combined through LDS (f32).
// ---------------------------------------------------------------------------
__global__ __launch_bounds__(512) void k_attn(
    const short* __restrict__ Qf, const short* __restrict__ Kf,
    const short* __restrict__ Vf, short* __restrict__ att) {
  __shared__ float Od[8][32][76];   // 76-pad: 16B-aligned rows, spread banks
  __shared__ float Ol[8][32];
  const int tid = threadIdx.x;
  const int w = tid >> 6, lane = tid & 63;
  const int c = lane & 31, h = lane >> 5;
  const int b = blockIdx.x >> 6;
  const int qg = blockIdx.x & 63;
  const size_t g0 = (size_t)b * 2048 + qg * 32;

  short8 qf0 = ldg8(Qf + (((size_t)b * 64 + qg) * 4 + 0) * 512 + lane * 8);
  short8 qf1 = ldg8(Qf + (((size_t)b * 64 + qg) * 4 + 1) * 512 + lane * 8);
  short8 qf2 = ldg8(Qf + (((size_t)b * 64 + qg) * 4 + 2) * 512 + lane * 8);
  short8 qf3 = ldg8(Qf + (((size_t)b * 64 + qg) * 4 + 3) * 512 + lane * 8);

  float lp = 0.0f;
  float16v acc0 = (float16v)0.0f;   // O^T d 0..31
  float16v acc1 = (float16v)0.0f;   // O^T d 32..63

  int kg = w * 8;                   // 8 subtiles of 32 keys = 256 keys/wave
  const short* kb = Kf + ((size_t)b * 64) * 2048 + lane * 8;
  const short* vb = Vf + ((size_t)b * 64) * 2048 + lane * 8;

#define ATTN_STEP(K0, K1, K2, K3, V0, V1, V2, V3)                              \
  do {                                                                         \
    float16v sf = (float16v)0.0f;                                              \
    sf = MFMA32(K0, qf0, sf);                                                  \
    sf = MFMA32(K1, qf1, sf);                                                  \
    sf = MFMA32(K2, qf2, sf);                                                  \
    sf = MFMA32(K3, qf3, sf);                                                  \
    unsigned wpk[8];                                                           \
    _Pragma("unroll")                                                          \
    for (int m = 0; m < 8; ++m) {                                              \
      float p0 = __builtin_amdgcn_exp2f(sf[2 * m]);                            \
      float p1 = __builtin_amdgcn_exp2f(sf[2 * m + 1]);                        \
      unsigned u0 = __builtin_bit_cast(unsigned, p0) & 0xFFFF0000u;            \
      unsigned u1 = __builtin_bit_cast(unsigned, p1) & 0xFFFF0000u;            \
      lp += __builtin_bit_cast(float, u0) + __builtin_bit_cast(float, u1);     \
      wpk[m] = (u0 >> 16) | u1;                                                \
    }                                                                          \
    plswap(wpk[0], wpk[2]);                                                    \
    plswap(wpk[1], wpk[3]);                                                    \
    plswap(wpk[4], wpk[6]);                                                    \
    plswap(wpk[5], wpk[7]);                                                    \
    union { unsigned u[4]; short8 s8; } bt0, bt1;                              \
    bt0.u[0] = wpk[0]; bt0.u[1] = wpk[1]; bt0.u[2] = wpk[2]; bt0.u[3] = wpk[3];\
    bt1.u[0] = wpk[4]; bt1.u[1] = wpk[5]; bt1.u[2] = wpk[6]; bt1.u[3] = wpk[7];\
    acc0 = MFMA32(V0, bt0.s8, acc0);                                           \
    acc0 = MFMA32(V1, bt1.s8, acc0);                                           \
    acc1 = MFMA32(V2, bt0.s8, acc1);                                           \
    acc1 = MFMA32(V3, bt1.s8, acc1);                                           \
  } while (0)

  const short* kpA = kb + (size_t)kg * 2048;
  const short* vpA = vb + (size_t)kg * 2048;
  short8 ka0 = ldg8(kpA), ka1 = ldg8(kpA + 512), ka2 = ldg8(kpA + 1024), ka3 = ldg8(kpA + 1536);
  short8 va0 = ldg8(vpA), va1 = ldg8(vpA + 512), va2 = ldg8(vpA + 1024), va3 = ldg8(vpA + 1536);

  for (int t = 0; t < 8; t += 2) {
    const short* kpB = kb + (size_t)(kg + 1) * 2048;
    const short* vpB = vb + (size_t)(kg + 1) * 2048;
    short8 kb0 = ldg8(kpB), kb1 = ldg8(kpB + 512), kb2 = ldg8(kpB + 1024), kb3 = ldg8(kpB + 1536);
    short8 vb0 = ldg8(vpB), vb1 = ldg8(vpB + 512), vb2 = ldg8(vpB + 1024), vb3 = ldg8(vpB + 1536);

    ATTN_STEP(ka0, ka1, ka2, ka3, va0, va1, va2, va3);

    if (t + 2 < 8) {
      const short* kpN = kb + (size_t)(kg + 2) * 2048;
      const short* vpN = vb + (size_t)(kg + 2) * 2048;
      ka0 = ldg8(kpN); ka1 = ldg8(kpN + 512); ka2 = ldg8(kpN + 1024); ka3 = ldg8(kpN + 1536);
      va0 = ldg8(vpN); va1 = ldg8(vpN + 512); va2 = ldg8(vpN + 1024); va3 = ldg8(vpN + 1536);
    }

    ATTN_STEP(kb0, kb1, kb2, kb3, vb0, vb1, vb2, vb3);
    kg += 2;
  }
#undef ATTN_STEP

  lp += __shfl_xor(lp, 32, 64);

  // write wave partials to LDS
#pragma unroll
  for (int g = 0; g < 4; ++g) {
    float4v a0, a1;
#pragma unroll
    for (int r = 0; r < 4; ++r) { a0[r] = acc0[4 * g + r]; a1[r] = acc1[4 * g + r]; }
    *(float4v*)(&Od[w][c][8 * g + 4 * h]) = a0;
    *(float4v*)(&Od[w][c][32 + 8 * g + 4 * h]) = a1;
  }
  if (h == 0) Ol[w][c] = lp;
  __syncthreads();

  // combine 8 wave-partials: thread = (q = tid>>4, d-quad = tid&15)
  {
    const int q = tid >> 4, dq = (tid & 15) * 4;
    float L = 0.0f;
    float4v o = (float4v)0.0f;
#pragma unroll
    for (int w2 = 0; w2 < 8; ++w2) {
      L += Ol[w2][q];
      o += *(const float4v*)(&Od[w2][q][dq]);
    }
    const float inv = 1.0f / L;
    short4v r;
#pragma unroll
    for (int j = 0; j < 4; ++j) r[j] = (short)f2bf(o[j] * inv);
    *(short4v*)(att + (g0 + q) * 64 + dq) = r;
  }
}

// ---------------------------------------------------------------------------
// k_out: out = att @ W_out + b_out (fp32 out). 512 blocks x 256 thr (4 waves).
// Block = 32 rows; wave = 32 rows x 192 cols. 2 blocks/CU.
// ---------------------------------------------------------------------------
__global__ __launch_bounds__(256) void k_out(
    const short* __restrict__ att, const short* __restrict__ WtO,
    const float* __restrict__ bo, float* __restrict__ out) {
  const int tid = threadIdx.x;
  const int w = tid >> 6, lane = tid & 63, lo = lane & 15, hi = lane >> 4;
  const int wc = w * 192;
  const int m0 = blockIdx.x * 32;

  short8 af[2][2];
#pragma unroll
  for (int rf = 0; rf < 2; ++rf) {
    const short* ap = att + (size_t)(m0 + rf * 16 + lo) * 64 + hi * 8;
    af[rf][0] = ldg8(ap);
    af[rf][1] = ldg8(ap + 32);
  }
  float4v acc[2][12];
#pragma unroll
  for (int rf = 0; rf < 2; ++rf)
#pragma unroll
    for (int c = 0; c < 12; ++c) acc[rf][c] = (float4v)0.0f;

#pragma unroll
  for (int c = 0; c < 12; ++c) {
    const short* bp = WtO + (size_t)(wc + c * 16 + lo) * 64 + hi * 8;
    short8 b0 = ldg8(bp);
    short8 b1 = ldg8(bp + 32);
#pragma unroll
    for (int rf = 0; rf < 2; ++rf) {
      acc[rf][c] = MFMA16(af[rf][0], b0, acc[rf][c]);
      acc[rf][c] = MFMA16(af[rf][1], b1, acc[rf][c]);
    }
  }
#pragma unroll
  for (int c = 0; c < 12; ++c) {
    const float bb = bo[wc + c * 16 + lo];
#pragma unroll
    for (int rf = 0; rf < 2; ++rf)
#pragma unroll
      for (int j = 0; j < 4; ++j)
        out[(size_t)(m0 + rf * 16 + hi * 4 + j) * 768 + wc + c * 16 + lo] =
            acc[rf][c][j] + bb;
  }
}

extern "C" void kernel_launch(void* const* d_in, const int* in_sizes, int n_in,
                              void* d_out, int out_size, void* d_ws, size_t ws_size,
                              hipStream_t stream) {
  (void)in_sizes; (void)n_in; (void)out_size; (void)ws_size;
  const float* x  = (const float*)d_in[0];
  const float* Wq = (const float*)d_in[1];
  const float* bq = (const float*)d_in[2];
  const float* Wo = (const float*)d_in[3];
  const float* bo = (const float*)d_in[4];
  float* out = (float*)d_out;

  char* ws = (char*)d_ws;
  short* Qf  = (short*)(ws);
  short* Kf  = (short*)(ws + 2097152);
  short* Vf  = (short*)(ws + 4194304);
  short* att = (short*)(ws + 6291456);
  short* Wt  = (short*)(ws + 8388608);
  short* WtO = (short*)(ws + 8978432);

  k_prep<<<84, 256, 0, stream>>>(Wq, Wo, Wt, WtO);
  k_qkv<<<512, 256, 0, stream>>>(x, Wt, bq, Qf, Kf, Vf);
  k_attn<<<512, 512, 0, stream>>>(Qf, Kf, Vf, att);
  k_out<<<512, 256, 0, stream>>>(att, WtO, bo, out);
}

// Round 9
// 61.907 us; speedup vs baseline: 2.1919x; 1.2653x over previous
//
#include <hip/hip_runtime.h>
#include <hip/hip_bf16.h>

// TinyAttention fused pipeline, bf16 MFMA path.
// Round 9: W_qkv pre-formatted to MFMA-fragment-native layout (Wtf) so every
// k_qkv W-load is a coalesced 1KB dwordx4 (was a 16-segment gather, issued
// 1.8M times). Everything else identical to round 8.
// ws layout (bytes):
//   Qf  bf16 [8][64][4][2][32][8]    @ 0         (2,097,152)  (q pre-scaled)
//   Kf  bf16 [8][64][4][2][32][8]    @ 2,097,152 (2,097,152)
//   Vf  bf16 [8][64][2][2][2][32][8] @ 4,194,304 (2,097,152)
//   att bf16 [16384][64]             @ 6,291,456 (2,097,152)
//   Wtf bf16 [24][4][6][64][8]       @ 8,388,608 (589,824)   (frag-native)
//   WtO bf16 [768][64]               @ 8,978,432 (98,304)

typedef __attribute__((ext_vector_type(8))) short short8;
typedef __attribute__((ext_vector_type(4))) short short4v;
typedef __attribute__((ext_vector_type(4))) float float4v;
typedef __attribute__((ext_vector_type(16))) float float16v;

#define MFMA16(a, b, c) __builtin_amdgcn_mfma_f32_16x16x32_bf16((a), (b), (c), 0, 0, 0)
#define MFMA32(a, b, c) __builtin_amdgcn_mfma_f32_32x32x16_bf16((a), (b), (c), 0, 0, 0)

// v_permlane32_swap_b32 a, b:  a[32+i] <-> b[i]  (VALU cross-lane, no DS)
static __device__ __forceinline__ void plswap(unsigned& a, unsigned& b) {
  asm("v_permlane32_swap_b32 %0, %1" : "+v"(a), "+v"(b));
}

static __device__ __forceinline__ unsigned short f2bf(float x) {
  union { float f; unsigned u; } v; v.f = x;
  return (unsigned short)((v.u + 0x7FFFu + ((v.u >> 16) & 1u)) >> 16);
}
static __device__ __forceinline__ short8 ldg8(const short* p) {
  return *(const short8*)p;
}

// ---------------------------------------------------------------------------
// k_prep:
//  blocks 0..95 : W_qkv f32 [1536][192] -> Wtf bf16 fragment-native,
//                 block = (kk = id>>2, w = id&3); frag(c,ks) lane(lo,hi) e =
//                 W_qkv[64kk + 32ks + 8hi + e][48w + 16c + lo]
//  blocks 96..107: W_out f32 [64][768] -> WtO bf16 [768][64]
// ---------------------------------------------------------------------------
__global__ __launch_bounds__(256) void k_prep(
    const float* __restrict__ Wq, const float* __restrict__ Wo,
    short* __restrict__ Wtf, short* __restrict__ WtO) {
  __shared__ float wl[64 * 52];
  __shared__ __align__(16) short tl[64 * 72];
  const int tid = threadIdx.x;
  int id = blockIdx.x;
  if (id < 96) {
    const int kk = id >> 2, w = id & 3;
    // stage W_qkv rows [64kk,64kk+64), cols [48w,48w+48) into LDS f32
    const int r = tid >> 2, cq = (tid & 3) * 12;
    const float* sp = Wq + (size_t)(kk * 64 + r) * 192 + w * 48 + cq;
    float4v a = *(const float4v*)(sp);
    float4v b = *(const float4v*)(sp + 4);
    float4v c4 = *(const float4v*)(sp + 8);
    float* dp = wl + r * 52 + cq;
    *(float4v*)(dp) = a; *(float4v*)(dp + 4) = b; *(float4v*)(dp + 8) = c4;
    __syncthreads();
    // emit 6 fragments x 64 lanes = 384 slots
#pragma unroll
    for (int i = 0; i < 2; ++i) {
      const int fid = i * 256 + tid;
      if (fid < 384) {
        const int frag = fid >> 6, lane = fid & 63;
        const int lo = lane & 15, hi = lane >> 4;
        const int c = frag >> 1, ks = frag & 1;
        short8 o;
#pragma unroll
        for (int e = 0; e < 8; ++e)
          o[e] = (short)f2bf(wl[(ks * 32 + hi * 8 + e) * 52 + c * 16 + lo]);
        *(short8*)(Wtf + ((((size_t)kk * 4 + w) * 6 + frag) << 9) + lane * 8) = o;
      }
    }
  } else {
    id -= 96;
    const int r = tid >> 2, cq = (tid & 3) * 16;
    const float* sp = Wo + (size_t)r * 768 + id * 64 + cq;
    float4v v0 = *(const float4v*)(sp);
    float4v v1 = *(const float4v*)(sp + 4);
    float4v v2 = *(const float4v*)(sp + 8);
    float4v v3 = *(const float4v*)(sp + 12);
    short8 s0, s1;
#pragma unroll
    for (int i = 0; i < 4; ++i) {
      s0[i] = (short)f2bf(v0[i]); s0[i + 4] = (short)f2bf(v1[i]);
      s1[i] = (short)f2bf(v2[i]); s1[i + 4] = (short)f2bf(v3[i]);
    }
    *(short8*)(tl + r * 72 + cq) = s0;
    *(short8*)(tl + r * 72 + cq + 8) = s1;
    __syncthreads();
    short8 o0, o1;
#pragma unroll
    for (int j = 0; j < 8; ++j) {
      o0[j] = tl[(cq + j) * 72 + r];
      o1[j] = tl[(cq + 8 + j) * 72 + r];
    }
    short* dp2 = WtO + (size_t)(id * 64 + r) * 64 + cq;
    *(short8*)(dp2) = o0;
    *(short8*)(dp2 + 8) = o1;
  }
}

// ---------------------------------------------------------------------------
// k_qkv: qkv = x @ W_qkv + b; writes fragment-native Qf/Kf/Vf (coalesced).
// 512 blocks x 256 thr (4 waves): block = 32 rows x 192 cols, wave = 32r x 48c.
// W-fragments now read coalesced from Wtf (1KB dwordx4, 6 contiguous frags).
// ---------------------------------------------------------------------------
__global__ __launch_bounds__(256) void k_qkv(
    const float* __restrict__ x, const short* __restrict__ Wtf,
    const float* __restrict__ bq, short* __restrict__ Qf,
    short* __restrict__ Kf, short* __restrict__ Vf) {
  __shared__ __align__(16) short xl[2][32 * 72];
  __shared__ __align__(16) short qbuf[32 * 72], kstg[32 * 72], vstg[32 * 72];
  const int tid = threadIdx.x;
  const int w = tid >> 6, lane = tid & 63, lo = lane & 15, hi = lane >> 4;
  const int m0 = blockIdx.x * 32;
  const float KSC = 0.18033688011112042f;  // (1/8) * log2(e)
  const int cb = w * 48;

  float4v acc[2][3];
#pragma unroll
  for (int r = 0; r < 2; ++r)
#pragma unroll
    for (int c = 0; c < 3; ++c) acc[r][c] = (float4v)0.0f;

  const int xr = tid >> 3, xc = (tid & 7) * 8;
  const float* xrow = x + (size_t)(m0 + xr) * 1536 + xc;
  short* xlw0 = &xl[0][xr * 72 + xc];
  short* xlw1 = &xl[1][xr * 72 + xc];

  // Wtf base for this wave: frag (kk, c, ks) at wbase + kk*12288 + (c*2+ks)*512
  const short* wbase = Wtf + ((size_t)w * 6) * 512 + lane * 8;

  float4v xv0 = *(const float4v*)(xrow + 0);
  float4v xv1 = *(const float4v*)(xrow + 4);
  short8 bcur[3][2];
#pragma unroll
  for (int c = 0; c < 3; ++c)
#pragma unroll
    for (int ks = 0; ks < 2; ++ks)
      bcur[c][ks] = ldg8(wbase + (c * 2 + ks) * 512);
  {
    short8 s0;
#pragma unroll
    for (int i = 0; i < 4; ++i) { s0[i] = (short)f2bf(xv0[i]); s0[i + 4] = (short)f2bf(xv1[i]); }
    *(short8*)(xlw0) = s0;
  }
  __syncthreads();

  for (int kk = 0; kk < 24; ++kk) {
    const int cur = kk & 1;
    short8 bnxt[3][2];
    if (kk < 23) {
      const int k1 = (kk + 1) * 64;
      xv0 = *(const float4v*)(xrow + k1 + 0);
      xv1 = *(const float4v*)(xrow + k1 + 4);
      const short* wn = wbase + (size_t)(kk + 1) * 12288;
#pragma unroll
      for (int c = 0; c < 3; ++c)
#pragma unroll
        for (int ks = 0; ks < 2; ++ks)
          bnxt[c][ks] = ldg8(wn + (c * 2 + ks) * 512);
    }
    const short* xb = &xl[cur][0];
#pragma unroll
    for (int r = 0; r < 2; ++r) {
      short8 a0 = *(const short8*)(xb + (r * 16 + lo) * 72 + hi * 8);
      short8 a1 = *(const short8*)(xb + (r * 16 + lo) * 72 + 32 + hi * 8);
#pragma unroll
      for (int c = 0; c < 3; ++c) {
        acc[r][c] = MFMA16(a0, bcur[c][0], acc[r][c]);
        acc[r][c] = MFMA16(a1, bcur[c][1], acc[r][c]);
      }
    }
    if (kk < 23) {
      short8 s0;
#pragma unroll
      for (int i = 0; i < 4; ++i) { s0[i] = (short)f2bf(xv0[i]); s0[i + 4] = (short)f2bf(xv1[i]); }
      *(short8*)(cur ? xlw0 : xlw1) = s0;
#pragma unroll
      for (int c = 0; c < 3; ++c) { bcur[c][0] = bnxt[c][0]; bcur[c][1] = bnxt[c][1]; }
    }
    __syncthreads();
  }

  float bb[3];
#pragma unroll
  for (int c = 0; c < 3; ++c) bb[c] = bq[cb + c * 16 + lo];

  const int b = m0 >> 11;
  const int row0 = m0 & 2047;  // batch-local 32-aligned row of block start

#pragma unroll
  for (int r = 0; r < 2; ++r)
#pragma unroll
    for (int c = 0; c < 3; ++c) {
      const int colb = cb + c * 16;
      short* buf = (colb < 64) ? qbuf : ((colb < 128) ? kstg : vstg);
      const int d0 = (colb & 63) + lo;
#pragma unroll
      for (int j = 0; j < 4; ++j) {
        float vv = acc[r][c][j] + bb[c];
        if (colb < 64) vv *= KSC;  // q: fold softmax scale (exp2 domain)
        buf[(r * 16 + hi * 4 + j) * 72 + d0] = (short)f2bf(vv);
      }
    }
  __syncthreads();

  // Q/K fragment stores: thread = (row rr 0..31, 8-d group dq)
  {
    const int rr = tid >> 3, dq = (tid & 7) * 8;
    const int t32 = row0 >> 5, i = dq >> 4, h = (dq >> 3) & 1;
    const size_t base = ((((size_t)b * 64 + t32) * 4 + i) * 2 + h) * 256 + rr * 8;
    *(short8*)(Qf + base) = *(const short8*)(qbuf + rr * 72 + dq);
    *(short8*)(Kf + base) = *(const short8*)(kstg + rr * 72 + dq);
  }

  // V fragment store: thread = (d=dr 0..63, 8-key group kq8), LDS transpose
  {
    const int dr = tid >> 2, kq8 = (tid & 3) * 8;
    short8 o0;
#pragma unroll
    for (int j = 0; j < 8; ++j) o0[j] = vstg[(kq8 + j) * 72 + dr];
    const int kg = row0 >> 5, s = (kq8 >> 4) & 1, h = (kq8 >> 3) & 1;
    const int dc = dr >> 5, c32 = dr & 31;
    short* vp = Vf + ((((((size_t)b * 64 + kg) * 2 + dc) * 2 + s) * 2 + h) * 32 + c32) * 8;
    *(short8*)(vp) = o0;
  }
}

// ---------------------------------------------------------------------------
// k_attn: in-block split-K flash attn. 512 blocks x 512 thr (8 waves).
// Wave w handles keys [256w, 256w+256) for the block's 32 q-rows with the
// 2-stage pipelined 32x32x16 loop; partials combined through LDS (f32).
// ---------------------------------------------------------------------------
__global__ __launch_bounds__(512) void k_attn(
    const short* __restrict__ Qf, const short* __restrict__ Kf,
    const short* __restrict__ Vf, short* __restrict__ att) {
  __shared__ float Od[8][32][76];   // 76-pad: 16B-aligned rows, spread banks
  __shared__ float Ol[8][32];
  const int tid = threadIdx.x;
  const int w = tid >> 6, lane = tid & 63;
  const int c = lane & 31, h = lane >> 5;
  const int b = blockIdx.x >> 6;
  const int qg = blockIdx.x & 63;
  const size_t g0 = (size_t)b * 2048 + qg * 32;

  short8 qf0 = ldg8(Qf + (((size_t)b * 64 + qg) * 4 + 0) * 512 + lane * 8);
  short8 qf1 = ldg8(Qf + (((size_t)b * 64 + qg) * 4 + 1) * 512 + lane * 8);
  short8 qf2 = ldg8(Qf + (((size_t)b * 64 + qg) * 4 + 2) * 512 + lane * 8);
  short8 qf3 = ldg8(Qf + (((size_t)b * 64 + qg) * 4 + 3) * 512 + lane * 8);

  float lp = 0.0f;
  float16v acc0 = (float16v)0.0f;   // O^T d 0..31
  float16v acc1 = (float16v)0.0f;   // O^T d 32..63

  int kg = w * 8;                   // 8 subtiles of 32 keys = 256 keys/wave
  const short* kb = Kf + ((size_t)b * 64) * 2048 + lane * 8;
  const short* vb = Vf + ((size_t)b * 64) * 2048 + lane * 8;

#define ATTN_STEP(K0, K1, K2, K3, V0, V1, V2, V3)                              \
  do {                                                                         \
    float16v sf = (float16v)0.0f;                                              \
    sf = MFMA32(K0, qf0, sf);                                                  \
    sf = MFMA32(K1, qf1, sf);                                                  \
    sf = MFMA32(K2, qf2, sf);                                                  \
    sf = MFMA32(K3, qf3, sf);                                                  \
    unsigned wpk[8];                                                           \
    _Pragma("unroll")                                                          \
    for (int m = 0; m < 8; ++m) {                                              \
      float p0 = __builtin_amdgcn_exp2f(sf[2 * m]);                            \
      float p1 = __builtin_amdgcn_exp2f(sf[2 * m + 1]);                        \
      unsigned u0 = __builtin_bit_cast(unsigned, p0) & 0xFFFF0000u;            \
      unsigned u1 = __builtin_bit_cast(unsigned, p1) & 0xFFFF0000u;            \
      lp += __builtin_bit_cast(float, u0) + __builtin_bit_cast(float, u1);     \
      wpk[m] = (u0 >> 16) | u1;                                                \
    }                                                                          \
    plswap(wpk[0], wpk[2]);                                                    \
    plswap(wpk[1], wpk[3]);                                                    \
    plswap(wpk[4], wpk[6]);                                                    \
    plswap(wpk[5], wpk[7]);                                                    \
    union { unsigned u[4]; short8 s8; } bt0, bt1;                              \
    bt0.u[0] = wpk[0]; bt0.u[1] = wpk[1]; bt0.u[2] = wpk[2]; bt0.u[3] = wpk[3];\
    bt1.u[0] = wpk[4]; bt1.u[1] = wpk[5]; bt1.u[2] = wpk[6]; bt1.u[3] = wpk[7];\
    acc0 = MFMA32(V0, bt0.s8, acc0);                                           \
    acc0 = MFMA32(V1, bt1.s8, acc0);                                           \
    acc1 = MFMA32(V2, bt0.s8, acc1);                                           \
    acc1 = MFMA32(V3, bt1.s8, acc1);                                           \
  } while (0)

  const short* kpA = kb + (size_t)kg * 2048;
  const short* vpA = vb + (size_t)kg * 2048;
  short8 ka0 = ldg8(kpA), ka1 = ldg8(kpA + 512), ka2 = ldg8(kpA + 1024), ka3 = ldg8(kpA + 1536);
  short8 va0 = ldg8(vpA), va1 = ldg8(vpA + 512), va2 = ldg8(vpA + 1024), va3 = ldg8(vpA + 1536);

  for (int t = 0; t < 8; t += 2) {
    const short* kpB = kb + (size_t)(kg + 1) * 2048;
    const short* vpB = vb + (size_t)(kg + 1) * 2048;
    short8 kb0 = ldg8(kpB), kb1 = ldg8(kpB + 512), kb2 = ldg8(kpB + 1024), kb3 = ldg8(kpB + 1536);
    short8 vb0 = ldg8(vpB), vb1 = ldg8(vpB + 512), vb2 = ldg8(vpB + 1024), vb3 = ldg8(vpB + 1536);

    ATTN_STEP(ka0, ka1, ka2, ka3, va0, va1, va2, va3);

    if (t + 2 < 8) {
      const short* kpN = kb + (size_t)(kg + 2) * 2048;
      const short* vpN = vb + (size_t)(kg + 2) * 2048;
      ka0 = ldg8(kpN); ka1 = ldg8(kpN + 512); ka2 = ldg8(kpN + 1024); ka3 = ldg8(kpN + 1536);
      va0 = ldg8(vpN); va1 = ldg8(vpN + 512); va2 = ldg8(vpN + 1024); va3 = ldg8(vpN + 1536);
    }

    ATTN_STEP(kb0, kb1, kb2, kb3, vb0, vb1, vb2, vb3);
    kg += 2;
  }
#undef ATTN_STEP

  lp += __shfl_xor(lp, 32, 64);

  // write wave partials to LDS
#pragma unroll
  for (int g = 0; g < 4; ++g) {
    float4v a0, a1;
#pragma unroll
    for (int r = 0; r < 4; ++r) { a0[r] = acc0[4 * g + r]; a1[r] = acc1[4 * g + r]; }
    *(float4v*)(&Od[w][c][8 * g + 4 * h]) = a0;
    *(float4v*)(&Od[w][c][32 + 8 * g + 4 * h]) = a1;
  }
  if (h == 0) Ol[w][c] = lp;
  __syncthreads();

  // combine 8 wave-partials: thread = (q = tid>>4, d-quad = tid&15)
  {
    const int q = tid >> 4, dq = (tid & 15) * 4;
    float L = 0.0f;
    float4v o = (float4v)0.0f;
#pragma unroll
    for (int w2 = 0; w2 < 8; ++w2) {
      L += Ol[w2][q];
      o += *(const float4v*)(&Od[w2][q][dq]);
    }
    const float inv = 1.0f / L;
    short4v r;
#pragma unroll
    for (int j = 0; j < 4; ++j) r[j] = (short)f2bf(o[j] * inv);
    *(short4v*)(att + (g0 + q) * 64 + dq) = r;
  }
}

// ---------------------------------------------------------------------------
// k_out: out = att @ W_out + b_out (fp32 out). 512 blocks x 256 thr (4 waves).
// Block = 32 rows; wave = 32 rows x 192 cols. 2 blocks/CU.
// ---------------------------------------------------------------------------
__global__ __launch_bounds__(256) void k_out(
    const short* __restrict__ att, const short* __restrict__ WtO,
    const float* __restrict__ bo, float* __restrict__ out) {
  const int tid = threadIdx.x;
  const int w = tid >> 6, lane = tid & 63, lo = lane & 15, hi = lane >> 4;
  const int wc = w * 192;
  const int m0 = blockIdx.x * 32;

  short8 af[2][2];
#pragma unroll
  for (int rf = 0; rf < 2; ++rf) {
    const short* ap = att + (size_t)(m0 + rf * 16 + lo) * 64 + hi * 8;
    af[rf][0] = ldg8(ap);
    af[rf][1] = ldg8(ap + 32);
  }
  float4v acc[2][12];
#pragma unroll
  for (int rf = 0; rf < 2; ++rf)
#pragma unroll
    for (int c = 0; c < 12; ++c) acc[rf][c] = (float4v)0.0f;

#pragma unroll
  for (int c = 0; c < 12; ++c) {
    const short* bp = WtO + (size_t)(wc + c * 16 + lo) * 64 + hi * 8;
    short8 b0 = ldg8(bp);
    short8 b1 = ldg8(bp + 32);
#pragma unroll
    for (int rf = 0; rf < 2; ++rf) {
      acc[rf][c] = MFMA16(af[rf][0], b0, acc[rf][c]);
      acc[rf][c] = MFMA16(af[rf][1], b1, acc[rf][c]);
    }
  }
#pragma unroll
  for (int c = 0; c < 12; ++c) {
    const float bb = bo[wc + c * 16 + lo];
#pragma unroll
    for (int rf = 0; rf < 2; ++rf)
#pragma unroll
      for (int j = 0; j < 4; ++j)
        out[(size_t)(m0 + rf * 16 + hi * 4 + j) * 768 + wc + c * 16 + lo] =
            acc[rf][c][j] + bb;
  }
}

extern "C" void kernel_launch(void* const* d_in, const int* in_sizes, int n_in,
                              void* d_out, int out_size, void* d_ws, size_t ws_size,
                              hipStream_t stream) {
  (void)in_sizes; (void)n_in; (void)out_size; (void)ws_size;
  const float* x  = (const float*)d_in[0];
  const float* Wq = (const float*)d_in[1];
  const float* bq = (const float*)d_in[2];
  const float* Wo = (const float*)d_in[3];
  const float* bo = (const float*)d_in[4];
  float* out = (float*)d_out;

  char* ws = (char*)d_ws;
  short* Qf  = (short*)(ws);
  short* Kf  = (short*)(ws + 2097152);
  short* Vf  = (short*)(ws + 4194304);
  short* att = (short*)(ws + 6291456);
  short* Wtf = (short*)(ws + 8388608);
  short* WtO = (short*)(ws + 8978432);

  k_prep<<<108, 256, 0, stream>>>(Wq, Wo, Wtf, WtO);
  k_qkv<<<512, 256, 0, stream>>>(x, Wtf, bq, Qf, Kf, Vf);
  k_attn<<<512, 512, 0, stream>>>(Qf, Kf, Vf, att);
  k_out<<<512, 256, 0, stream>>>(att, WtO, bo, out);
}